// Round 8
// baseline (1109.899 us; speedup 1.0000x reference)
//
#include <hip/hip_runtime.h>
#include <math.h>

// Shapes: B=16, x[16,256,256,3], h1[16,128,128,128], h2[16,64,64,128],
// z_e/z_q[65536,64], g1[16,128,128,128](bf16), x_rec[16,256,256,3], K=1024.
//
// R8: quarter-major LDS panels [q][row] (row stride 16B) for all MFMA kernels.
// The old [row][32ci] layout had 64B row stride -> 8-way bank conflicts on
// every fragment ds_read_b128 (the 1.697e7 counter). Staging instruction
// count unchanged (each async16 now covers 64 rows of one ci-quarter).
// convt2 reverted to R5 phase structure (4 phases, 8 barriers) + swizzle +
// shuffle epilogue.

typedef __attribute__((ext_vector_type(8))) short short8;
typedef __attribute__((ext_vector_type(4))) float f32x4;

__device__ __forceinline__ float gelu_f(float x) {          // encoder (exact path)
    float x3 = x*x*x;
    return 0.5f*x*(1.0f + tanhf(0.7978845608028654f*(x + 0.044715f*x3)));
}
__device__ __forceinline__ float gelu_fast(float x) {       // decoder only
    float t = __expf(-1.5957691216057308f*(x + 0.044715f*x*x*x));
    return x / (1.f + t);
}

__device__ __forceinline__ unsigned short f2bf(float f) {
    unsigned int u = __float_as_uint(f);
    u = (u + 0x7FFFu + ((u >> 16) & 1u)) >> 16;   // RNE
    return (unsigned short)u;
}
__device__ __forceinline__ float bf2f(unsigned short h) {
    return __uint_as_float(((unsigned int)h) << 16);
}

typedef const __attribute__((address_space(1))) unsigned int* gp_t;
typedef __attribute__((address_space(3))) unsigned int* lp_t;
__device__ __forceinline__ void async16(const void* g, void* l) {
    __builtin_amdgcn_global_load_lds((gp_t)g, (lp_t)l, 16, 0, 0);
}

// ---------------- conv1: x[16,256,256,3] -> h1 hi/lo bf16 planes, 4x4 s2 SAME, GELU
__global__ __launch_bounds__(256) void k_conv1(const float* __restrict__ x,
        const float* __restrict__ w, const float* __restrict__ bias,
        unsigned short* __restrict__ outh, unsigned short* __restrict__ outl) {
    __shared__ __align__(16) float ws[48*128];
    __shared__ __align__(16) float xs[4][390];
    const int tid = threadIdx.x;
    const int blk = blockIdx.x;
    const int oxt = blk & 1;
    const int oy  = (blk >> 1) & 127;
    const int b   = blk >> 8;
    const int cg = tid & 15, pg = tid >> 4;
    const int c0a = cg*4, c0b = 64 + cg*4;
    const int p0 = pg*4;
    const int ox0 = oxt*64;

    for (int i = tid; i < 6144; i += 256) ws[i] = w[i];
    for (int r = 0; r < 4; ++r) {
        int iy = 2*oy + r - 1;
        bool yok = (unsigned)iy < 256u;
        const float* xrow = x + ((size_t)(b*256) + iy)*256*3;
        for (int i = tid; i < 390; i += 256) {
            int ixl = i/3, ci = i - ixl*3;
            int ix = 2*ox0 - 1 + ixl;
            xs[r][i] = (yok && (unsigned)ix < 256u) ? xrow[(size_t)ix*3 + ci] : 0.f;
        }
    }
    __syncthreads();

    float acc[4][8];
    #pragma unroll
    for (int j = 0; j < 4; ++j)
        #pragma unroll
        for (int i = 0; i < 8; ++i) acc[j][i] = 0.f;

    #pragma unroll 6
    for (int pos = 0; pos < 48; ++pos) {
        int r = pos/12, tc = pos - r*12;
        int t = tc/3,  ci = tc - t*3;
        float4 w0 = *(const float4*)&ws[pos*128 + c0a];
        float4 w1 = *(const float4*)&ws[pos*128 + c0b];
        #pragma unroll
        for (int j = 0; j < 4; ++j) {
            float av = xs[r][(2*(p0+j) + t)*3 + ci];
            acc[j][0] += av*w0.x; acc[j][1] += av*w0.y;
            acc[j][2] += av*w0.z; acc[j][3] += av*w0.w;
            acc[j][4] += av*w1.x; acc[j][5] += av*w1.y;
            acc[j][6] += av*w1.z; acc[j][7] += av*w1.w;
        }
    }
    float bv[8];
    #pragma unroll
    for (int i = 0; i < 4; ++i) { bv[i] = bias[c0a+i]; bv[4+i] = bias[c0b+i]; }
    #pragma unroll
    for (int j = 0; j < 4; ++j) {
        int ox = ox0 + p0 + j;
        size_t base = (((size_t)(b*128) + oy)*128 + ox)*128;
        ushort4 ha, hb, la, lb;
        float y;
        y = gelu_f(acc[j][0]+bv[0]); ha.x = f2bf(y); la.x = f2bf(y - bf2f(ha.x));
        y = gelu_f(acc[j][1]+bv[1]); ha.y = f2bf(y); la.y = f2bf(y - bf2f(ha.y));
        y = gelu_f(acc[j][2]+bv[2]); ha.z = f2bf(y); la.z = f2bf(y - bf2f(ha.z));
        y = gelu_f(acc[j][3]+bv[3]); ha.w = f2bf(y); la.w = f2bf(y - bf2f(ha.w));
        y = gelu_f(acc[j][4]+bv[4]); hb.x = f2bf(y); lb.x = f2bf(y - bf2f(hb.x));
        y = gelu_f(acc[j][5]+bv[5]); hb.y = f2bf(y); lb.y = f2bf(y - bf2f(hb.y));
        y = gelu_f(acc[j][6]+bv[6]); hb.z = f2bf(y); lb.z = f2bf(y - bf2f(hb.z));
        y = gelu_f(acc[j][7]+bv[7]); hb.w = f2bf(y); lb.w = f2bf(y - bf2f(hb.w));
        *(ushort4*)&outh[base + c0a] = ha;
        *(ushort4*)&outh[base + c0b] = hb;
        *(ushort4*)&outl[base + c0a] = la;
        *(ushort4*)&outl[base + c0b] = lb;
    }
}

// ---------------- conv2 (split-bf16 MFMA, async16, 512 thr, quarter-major LDS)
// Block (b, oy-pair): M=128 px, N=128 co. 8 waves 4Mx2N, wave tile 32x64.
// Plane layout: [kc(2)][q(4)][row(128)] x 16B  (row stride 16B -> 2-way free).
__global__ __launch_bounds__(512) void k_conv2m(const unsigned short* __restrict__ h1h,
        const unsigned short* __restrict__ h1l,
        const unsigned short* __restrict__ w2h, const unsigned short* __restrict__ w2l,
        const float* __restrict__ bias, const float* __restrict__ zsc,
        float* __restrict__ out) {
    __shared__ __align__(16) unsigned short Ah[2*4*128*8];
    __shared__ __align__(16) unsigned short Al[2*4*128*8];
    __shared__ __align__(16) unsigned short Bh[2*4*128*8];
    __shared__ __align__(16) unsigned short Bl[2*4*128*8];
    const int tid = threadIdx.x;
    const int yy = blockIdx.x & 31;
    const int b  = blockIdx.x >> 5;
    const int oy0 = yy*2;
    const int lane = tid & 63, l15 = lane & 15, q = lane >> 4;
    const int wid = tid >> 6;                  // 0..7
    const int wm = wid >> 1, wn = wid & 1;     // wave tile 32x64

    f32x4 acc[2][4];
    #pragma unroll
    for (int fm = 0; fm < 2; ++fm)
        #pragma unroll
        for (int fn = 0; fn < 4; ++fn) acc[fm][fn] = (f32x4){0.f,0.f,0.f,0.f};

    for (int tap = 0; tap < 16; ++tap) {
        int r = tap >> 2, t = tap & 3;
        for (int cs = 0; cs < 2; ++cs) {
            __syncthreads();
            #pragma unroll
            for (int j = 0; j < 8; ++j) {
                int id = wid*8 + j;           // 0..63, wave-uniform
                int plane = id >> 4;          // 0 Ah, 1 Al, 2 Bh, 3 Bl
                int r4 = id & 15;
                int kc_ = r4 >> 3, q_ = (r4 >> 1) & 3, h = r4 & 1;
                int ci = cs*64 + kc_*32 + q_*8;
                int ldsoff = kc_*4096 + q_*1024 + h*512;   // ushort units
                if (plane < 2) {
                    int iy = 2*(oy0 + h) + r - 1, ix = 2*lane + t - 1;
                    bool ok = (unsigned)iy < 128u && (unsigned)ix < 128u;
                    const unsigned short* base = plane ? h1l : h1h;
                    const unsigned short* gp = ok
                        ? base + (((size_t)(b*128)+iy)*128+ix)*128 + ci
                        : (const unsigned short*)zsc;
                    async16(gp, (plane ? Al : Ah) + ldsoff);
                } else {
                    int co = h*64 + lane;
                    const unsigned short* base = (plane == 3) ? w2l : w2h;
                    async16(base + ((size_t)tap*128 + co)*128 + ci,
                            ((plane == 3) ? Bl : Bh) + ldsoff);
                }
            }
            __syncthreads();
            #pragma unroll
            for (int kc = 0; kc < 2; ++kc) {
                short8 ah[2], al[2], bh[4], bl[4];
                #pragma unroll
                for (int fm = 0; fm < 2; ++fm) {
                    int off = kc*4096 + q*1024 + (wm*32 + fm*16 + l15)*8;
                    ah[fm] = *(const short8*)&Ah[off];
                    al[fm] = *(const short8*)&Al[off];
                }
                #pragma unroll
                for (int fn = 0; fn < 4; ++fn) {
                    int off = kc*4096 + q*1024 + (wn*64 + fn*16 + l15)*8;
                    bh[fn] = *(const short8*)&Bh[off];
                    bl[fn] = *(const short8*)&Bl[off];
                }
                #pragma unroll
                for (int fm = 0; fm < 2; ++fm)
                    #pragma unroll
                    for (int fn = 0; fn < 4; ++fn) {
                        acc[fm][fn] = __builtin_amdgcn_mfma_f32_16x16x32_bf16(
                            ah[fm], bh[fn], acc[fm][fn], 0, 0, 0);
                        acc[fm][fn] = __builtin_amdgcn_mfma_f32_16x16x32_bf16(
                            al[fm], bh[fn], acc[fm][fn], 0, 0, 0);
                        acc[fm][fn] = __builtin_amdgcn_mfma_f32_16x16x32_bf16(
                            ah[fm], bl[fn], acc[fm][fn], 0, 0, 0);
                    }
            }
        }
    }
    float bv[4];
    #pragma unroll
    for (int fn = 0; fn < 4; ++fn) bv[fn] = bias[wn*64 + fn*16 + l15];
    #pragma unroll
    for (int fm = 0; fm < 2; ++fm)
        #pragma unroll
        for (int rg = 0; rg < 4; ++rg) {
            int px = wm*32 + fm*16 + q*4 + rg;
            int oy = oy0 + (px >> 6), ox = px & 63;
            float* o = out + (((size_t)(b*64) + oy)*64 + ox)*128;
            #pragma unroll
            for (int fn = 0; fn < 4; ++fn)
                o[wn*64 + fn*16 + l15] = gelu_f(acc[fm][fn][rg] + bv[fn]);
        }
}

// ---------------- conv3 (1x1, 128->64, f32): h2 -> z_e [65536,64]
__global__ __launch_bounds__(256) void k_conv3(const float* __restrict__ in,
        const float* __restrict__ w, const float* __restrict__ bias,
        float* __restrict__ out) {
    __shared__ __align__(16) float xs[128*33];
    __shared__ __align__(16) float wb[32*64];
    const int tid = threadIdx.x;
    const size_t pix0 = (size_t)blockIdx.x * 128;
    const int cg = tid & 7, pg = tid >> 3;
    const int c0a = cg*4, c0b = 32 + cg*4;
    const int p0 = pg*4;

    float acc[4][8];
    #pragma unroll
    for (int j = 0; j < 4; ++j)
        #pragma unroll
        for (int i = 0; i < 8; ++i) acc[j][i] = 0.f;

    for (int cs = 0; cs < 4; ++cs) {
        __syncthreads();
        for (int i = tid; i < 4096; i += 256) {
            int p = i >> 5, ci = i & 31;
            xs[p*33 + ci] = in[(pix0 + p)*128 + cs*32 + ci];
        }
        for (int i = tid; i < 2048; i += 256) {
            int ci = i >> 6, c = i & 63;
            wb[i] = w[(size_t)(cs*32 + ci)*64 + c];
        }
        __syncthreads();
        #pragma unroll 8
        for (int ci = 0; ci < 32; ++ci) {
            float a_[4];
            #pragma unroll
            for (int j = 0; j < 4; ++j) a_[j] = xs[(p0+j)*33 + ci];
            float4 b0 = *(const float4*)&wb[ci*64 + c0a];
            float4 b1 = *(const float4*)&wb[ci*64 + c0b];
            #pragma unroll
            for (int j = 0; j < 4; ++j) {
                acc[j][0] += a_[j]*b0.x; acc[j][1] += a_[j]*b0.y;
                acc[j][2] += a_[j]*b0.z; acc[j][3] += a_[j]*b0.w;
                acc[j][4] += a_[j]*b1.x; acc[j][5] += a_[j]*b1.y;
                acc[j][6] += a_[j]*b1.z; acc[j][7] += a_[j]*b1.w;
            }
        }
    }
    #pragma unroll
    for (int j = 0; j < 4; ++j) {
        float* o = out + (pix0 + p0 + j)*64;
        float4 va, vb;
        va.x = acc[j][0]+bias[c0a+0]; va.y = acc[j][1]+bias[c0a+1];
        va.z = acc[j][2]+bias[c0a+2]; va.w = acc[j][3]+bias[c0a+3];
        vb.x = acc[j][4]+bias[c0b+0]; vb.y = acc[j][5]+bias[c0b+1];
        vb.z = acc[j][6]+bias[c0b+2]; vb.w = acc[j][7]+bias[c0b+3];
        *(float4*)&o[c0a] = va;
        *(float4*)&o[c0b] = vb;
    }
}

// ---------------- VQ: f32 (exact), writes z_q as bf16 for the decoder
__global__ __launch_bounds__(256) void k_vq(const float* __restrict__ ze,
        const float* __restrict__ cb, unsigned short* __restrict__ zqb,
        float* __restrict__ tok, float* __restrict__ loss_acc) {
    __shared__ __align__(16) float zs[64*65];
    __shared__ __align__(16) float bt[64*132];
    __shared__ float es[128];
    __shared__ float z2s[64];
    __shared__ float rmin[64*16];
    __shared__ int   ridx[64*16];
    __shared__ int   widx[64];
    __shared__ float wsum[4];
    const int tid = threadIdx.x;
    const size_t tok0 = (size_t)blockIdx.x * 64;
    const int cg = tid & 15, pg = tid >> 4;
    const int k0a = cg*4, k0b = 64 + cg*4;
    const int t0 = pg*4;

    for (int i = tid; i < 4096; i += 256) {
        int tk = i >> 6, d = i & 63;
        zs[tk*65 + d] = ze[(tok0 + tk)*64 + d];
    }
    __syncthreads();
    if (tid < 64) {
        float s = 0.f;
        for (int d = 0; d < 64; ++d) { float v = zs[tid*65 + d]; s += v*v; }
        z2s[tid] = s;
    }

    float bmin[4] = {3.4e38f,3.4e38f,3.4e38f,3.4e38f};
    int   bidx[4] = {0,0,0,0};

    for (int ch = 0; ch < 8; ++ch) {
        __syncthreads();
        for (int i = tid; i < 8192; i += 256) {
            int k = i >> 6, d = i & 63;
            bt[d*132 + k] = cb[((size_t)(ch*128) + k)*64 + d];
        }
        __syncthreads();
        if (tid < 128) {
            float s = 0.f;
            for (int d = 0; d < 64; ++d) { float v = bt[d*132 + tid]; s += v*v; }
            es[tid] = s;
        }
        __syncthreads();
        float acc[4][8];
        #pragma unroll
        for (int j = 0; j < 4; ++j)
            #pragma unroll
            for (int i = 0; i < 8; ++i) acc[j][i] = 0.f;
        #pragma unroll 4
        for (int d = 0; d < 64; ++d) {
            float a_[4];
            #pragma unroll
            for (int j = 0; j < 4; ++j) a_[j] = zs[(t0+j)*65 + d];
            float4 b0 = *(const float4*)&bt[d*132 + k0a];
            float4 b1 = *(const float4*)&bt[d*132 + k0b];
            #pragma unroll
            for (int j = 0; j < 4; ++j) {
                acc[j][0] += a_[j]*b0.x; acc[j][1] += a_[j]*b0.y;
                acc[j][2] += a_[j]*b0.z; acc[j][3] += a_[j]*b0.w;
                acc[j][4] += a_[j]*b1.x; acc[j][5] += a_[j]*b1.y;
                acc[j][6] += a_[j]*b1.z; acc[j][7] += a_[j]*b1.w;
            }
        }
        #pragma unroll
        for (int j = 0; j < 4; ++j) {
            float z2 = z2s[t0+j];
            #pragma unroll
            for (int i = 0; i < 4; ++i) {
                float dist = (z2 + es[k0a+i]) - 2.f*acc[j][i];
                int idx = ch*128 + k0a + i;
                if (dist < bmin[j]) { bmin[j] = dist; bidx[j] = idx; }
            }
            #pragma unroll
            for (int i = 0; i < 4; ++i) {
                float dist = (z2 + es[k0b+i]) - 2.f*acc[j][4+i];
                int idx = ch*128 + k0b + i;
                if (dist < bmin[j]) { bmin[j] = dist; bidx[j] = idx; }
            }
        }
    }
    #pragma unroll
    for (int j = 0; j < 4; ++j) {
        rmin[(t0+j)*16 + cg] = bmin[j];
        ridx[(t0+j)*16 + cg] = bidx[j];
    }
    __syncthreads();
    if (tid < 64) {
        float bv = rmin[tid*16]; int bi = ridx[tid*16];
        for (int g = 1; g < 16; ++g) {
            float v = rmin[tid*16 + g]; int ii = ridx[tid*16 + g];
            if (v < bv || (v == bv && ii < bi)) { bv = v; bi = ii; }
        }
        widx[tid] = bi;
        tok[tok0 + tid] = (float)bi;
    }
    __syncthreads();
    float lsum = 0.f;
    for (int i = tid; i < 4096; i += 256) {
        int tk = i >> 6, d = i & 63;
        float v = cb[(size_t)widx[tk]*64 + d];
        zqb[(tok0 + tk)*64 + d] = f2bf(v);
        float diff = v - zs[tk*65 + d];
        lsum += diff*diff;
    }
    #pragma unroll
    for (int off = 32; off > 0; off >>= 1) lsum += __shfl_down(lsum, off, 64);
    if ((tid & 63) == 0) wsum[tid >> 6] = lsum;
    __syncthreads();
    if (tid == 0) atomicAdd(loss_acc, wsum[0]+wsum[1]+wsum[2]+wsum[3]);
}

// ---------------- weight prep kernels
__global__ __launch_bounds__(256) void k_wsplit2(const float* __restrict__ w,
        unsigned short* __restrict__ hi, unsigned short* __restrict__ lo) {
    int i = blockIdx.x*256 + threadIdx.x;        // 262144
    int rt = i >> 14, rem = i & 16383;
    int co = rem >> 7, ci = rem & 127;
    float v = w[((size_t)rt*128 + ci)*128 + co];
    unsigned short h = f2bf(v);
    hi[i] = h;
    lo[i] = f2bf(v - bf2f(h));
}
__global__ __launch_bounds__(256) void k_wcvt2(const float* __restrict__ w,
        unsigned short* __restrict__ o) {
    int i = blockIdx.x*256 + threadIdx.x;        // 262144
    int rt = i >> 14, rem = i & 16383;
    int co = rem >> 7, ci = rem & 127;
    o[i] = f2bf(w[((size_t)rt*128 + ci)*128 + co]);
}
__global__ __launch_bounds__(256) void k_wcvt1(const float* __restrict__ w,
        unsigned short* __restrict__ o) {
    int i = blockIdx.x*256 + threadIdx.x;        // 131072
    int rt = i >> 13, rem = i & 8191;
    int co = rem >> 6, ci = rem & 63;
    o[i] = f2bf(w[((size_t)rt*64 + ci)*128 + co]);
}

// ---------------- convT1 (bf16 MFMA, async16, quarter-major): zqb -> g1b, GELU
// Plane layout: [kc(2)][q(4)][row(128)] x 16B.
__global__ __launch_bounds__(256) void k_convt1m(const unsigned short* __restrict__ zqb,
        const unsigned short* __restrict__ w1b, const float* __restrict__ bias,
        const float* __restrict__ zsc, unsigned short* __restrict__ out) {
    __shared__ __align__(16) unsigned short A[2*4*128*8];
    __shared__ __align__(16) unsigned short Bm[2*4*128*8];
    const int tid = threadIdx.x;
    const int par = blockIdx.x & 1;
    const int ey  = (blockIdx.x >> 1) & 1;
    const int qq  = (blockIdx.x >> 2) & 31;
    const int b   = blockIdx.x >> 7;
    const int q0  = qq*2;
    const int lane = tid & 63, l15 = lane & 15, q = lane >> 4;
    const int wid = tid >> 6, wm = wid >> 1, wn = wid & 1;

    f32x4 acc[4][4];
    #pragma unroll
    for (int fm = 0; fm < 4; ++fm)
        #pragma unroll
        for (int fn = 0; fn < 4; ++fn) acc[fm][fn] = (f32x4){0.f,0.f,0.f,0.f};

    for (int tap = 0; tap < 4; ++tap) {
        int rr = tap >> 1, tt = tap & 1;
        int rt = (ey + 2*rr)*4 + (par + 2*tt);
        __syncthreads();
        #pragma unroll
        for (int j = 0; j < 8; ++j) {
            int id = wid*8 + j;               // 0..31, wave-uniform
            int plane = id >> 4;              // 0 A, 1 B
            int r4 = id & 15;
            int kc_ = r4 >> 3, q_ = (r4 >> 1) & 3, h = r4 & 1;
            int ci = kc_*32 + q_*8;
            int ldsoff = kc_*4096 + q_*1024 + h*512;
            if (plane == 0) {
                int qv = q0 + h;
                int iy = qv + ey - 1 + rr, ix = lane + par - 1 + tt;
                bool ok = (unsigned)iy < 64u && (unsigned)ix < 64u;
                const unsigned short* gp = ok
                    ? zqb + (((size_t)(b*64)+iy)*64+ix)*64 + ci
                    : (const unsigned short*)zsc;
                async16(gp, A + ldsoff);
            } else {
                int co = h*64 + lane;
                async16(w1b + ((size_t)rt*128 + co)*64 + ci, Bm + ldsoff);
            }
        }
        __syncthreads();
        #pragma unroll
        for (int kc = 0; kc < 2; ++kc) {
            short8 af[4], bf[4];
            #pragma unroll
            for (int fm = 0; fm < 4; ++fm)
                af[fm] = *(const short8*)&A[kc*4096 + q*1024 + (wm*64 + fm*16 + l15)*8];
            #pragma unroll
            for (int fn = 0; fn < 4; ++fn)
                bf[fn] = *(const short8*)&Bm[kc*4096 + q*1024 + (wn*64 + fn*16 + l15)*8];
            #pragma unroll
            for (int fm = 0; fm < 4; ++fm)
                #pragma unroll
                for (int fn = 0; fn < 4; ++fn)
                    acc[fm][fn] = __builtin_amdgcn_mfma_f32_16x16x32_bf16(
                        af[fm], bf[fn], acc[fm][fn], 0, 0, 0);
        }
    }
    float bv[4];
    #pragma unroll
    for (int fn = 0; fn < 4; ++fn) bv[fn] = bias[wn*64 + fn*16 + l15];
    #pragma unroll
    for (int fm = 0; fm < 4; ++fm)
        #pragma unroll
        for (int rg = 0; rg < 4; ++rg) {
            int px = wm*64 + fm*16 + q*4 + rg;
            int qv = q0 + (px >> 6), p = px & 63;
            int oy = 2*qv + ey, ox = par + 2*p;
            unsigned short* o = out + (((size_t)(b*128) + oy)*128 + ox)*128;
            #pragma unroll
            for (int fn = 0; fn < 4; ++fn)
                o[wn*64 + fn*16 + l15] = f2bf(gelu_fast(acc[fm][fn][rg] + bv[fn]));
        }
}

// ---------------- convT2 (bf16 MFMA, quarter-major, R5 phase structure) + 1x1
// Block (b,oy,par): M=128 px, N=128 co, K=4 taps x 128 ci (4 kc phases).
// LDS: A[rr(2)][q(4)][132] + B[tap(4)][q(4)][128], 16B rows.
__global__ __launch_bounds__(256) void k_convt2(const unsigned short* __restrict__ g1b,
        const unsigned short* __restrict__ wtb, const float* __restrict__ b2,
        const float* __restrict__ w3, const float* __restrict__ b3,
        const float* __restrict__ zsc, float* __restrict__ xrec) {
    union SM {
        struct {
            unsigned short A[2*4*132*8];     // 16896 B
            unsigned short B4[4*4*128*8];    // 32768 B
        } s;
        float red[128*2*3];                  // 3072 B
    };
    __shared__ __align__(16) union SM sm;
    const int tid = threadIdx.x;
    // XCD swizzle: consecutive same-XCD blocks walk par, then qy (L2 row reuse)
    const int gblk = blockIdx.x;
    const int xcd = gblk & 7;
    const int s_  = gblk >> 3;                 // 0..1023
    const int par = s_ & 1;
    const int qy  = (s_ >> 1) & 127;
    const int ey  = (s_ >> 8) & 1;
    const int b   = xcd*2 + (s_ >> 9);
    const int oy  = qy*2 + ey;
    const int lane = tid & 63, l15 = lane & 15, q = lane >> 4;
    const int wid = tid >> 6, wm = wid >> 1, wn = wid & 1;
    const int iy0 = qy + ey - 1;

    f32x4 acc[4][4];
    #pragma unroll
    for (int fm = 0; fm < 4; ++fm)
        #pragma unroll
        for (int fn = 0; fn < 4; ++fn) acc[fm][fn] = (f32x4){0.f,0.f,0.f,0.f};

    // zero halo rows (stored idx 0 and 129 per (rr,q)) — 16 slots of 16B
    if (tid < 16) {
        int rr = tid >> 3, q_ = (tid >> 1) & 3, side = tid & 1;
        int idx = side ? 129 : 0;
        *(uint4*)&sm.s.A[rr*4224 + q_*1056 + idx*8] = make_uint4(0,0,0,0);
    }

    int rt_tab[4];
    #pragma unroll
    for (int tap = 0; tap < 4; ++tap) {
        int rr = tap >> 1, tt = tap & 1;
        rt_tab[tap] = (ey + 2*rr)*4 + (par + 2*tt);
    }

    for (int kc = 0; kc < 4; ++kc) {
        __syncthreads();   // protect prior reads (and halo zeros, 1st iter)
        #pragma unroll
        for (int j = 0; j < 12; ++j) {
            int id = wid*12 + j;              // 0..47, wave-uniform
            if (id < 16) {                    // A: rr(2) x q(4) x h(2)
                int rr = id >> 3, q_ = (id >> 1) & 3, h = id & 1;
                int iy = iy0 + rr;
                bool yok = (unsigned)iy < 128u;
                const unsigned short* gp = yok
                    ? g1b + (((size_t)(b*128)+iy)*128 + (h*64 + lane))*128 + kc*32 + q_*8
                    : (const unsigned short*)zsc;
                async16(gp, &sm.s.A[rr*4224 + q_*1056 + (1 + h*64)*8]);
            } else {                          // B: tap(4) x q(4) x h(2)
                int idb = id - 16;
                int tap = idb >> 3, q_ = (idb >> 1) & 3, h = idb & 1;
                int co = h*64 + lane;
                async16(wtb + (size_t)rt_tab[tap]*16384 + co*128 + kc*32 + q_*8,
                        &sm.s.B4[tap*4096 + q_*1024 + h*512]);
            }
        }
        __syncthreads();
        #pragma unroll
        for (int tap = 0; tap < 4; ++tap) {
            int rr = tap >> 1, tt = tap & 1;
            short8 af[4], bf[4];
            #pragma unroll
            for (int fm = 0; fm < 4; ++fm)
                af[fm] = *(const short8*)&sm.s.A[
                    rr*4224 + q*1056 + (wm*64 + fm*16 + l15 + par + tt)*8];
            #pragma unroll
            for (int fn = 0; fn < 4; ++fn)
                bf[fn] = *(const short8*)&sm.s.B4[
                    tap*4096 + q*1024 + (wn*64 + fn*16 + l15)*8];
            #pragma unroll
            for (int fm = 0; fm < 4; ++fm)
                #pragma unroll
                for (int fn = 0; fn < 4; ++fn)
                    acc[fm][fn] = __builtin_amdgcn_mfma_f32_16x16x32_bf16(
                        af[fm], bf[fn], acc[fm][fn], 0, 0, 0);
        }
    }

    // epilogue: GELU(acc+b2), project 128->3, shuffle-reduce over l15 (co dim)
    float b2v[4];
    float w3v[4][3];
    #pragma unroll
    for (int fn = 0; fn < 4; ++fn) {
        int co = wn*64 + fn*16 + l15;
        b2v[fn] = b2[co];
        w3v[fn][0] = w3[co*3+0]; w3v[fn][1] = w3[co*3+1]; w3v[fn][2] = w3[co*3+2];
    }
    __syncthreads();
    #pragma unroll
    for (int fm = 0; fm < 4; ++fm) {
        #pragma unroll
        for (int rg = 0; rg < 4; ++rg) {
            float s0 = 0.f, s1 = 0.f, s2 = 0.f;
            #pragma unroll
            for (int fn = 0; fn < 4; ++fn) {
                float y = gelu_fast(acc[fm][fn][rg] + b2v[fn]);
                s0 += y*w3v[fn][0]; s1 += y*w3v[fn][1]; s2 += y*w3v[fn][2];
            }
            #pragma unroll
            for (int m = 1; m < 16; m <<= 1) {
                s0 += __shfl_xor(s0, m, 64);
                s1 += __shfl_xor(s1, m, 64);
                s2 += __shfl_xor(s2, m, 64);
            }
            if (l15 == 0) {
                int px = wm*64 + fm*16 + q*4 + rg;
                sm.red[(px*2 + wn)*3 + 0] = s0;
                sm.red[(px*2 + wn)*3 + 1] = s1;
                sm.red[(px*2 + wn)*3 + 2] = s2;
            }
        }
    }
    __syncthreads();
    for (int o = tid; o < 384; o += 256) {
        int px = o/3, jj = o - px*3;
        float s = b3[jj] + sm.red[(px*2 + 0)*3 + jj] + sm.red[(px*2 + 1)*3 + jj];
        xrec[(((size_t)(b*256) + oy)*256 + (par + 2*px))*3 + jj] = s;
    }
}

__global__ void k_zero(float* lacc, float* zsc) {
    if (threadIdx.x == 0) lacc[0] = 0.f;
    if (threadIdx.x < 4) zsc[threadIdx.x] = 0.f;
}

__global__ void k_finalize(const float* __restrict__ loss_acc, float* __restrict__ o) {
    if (threadIdx.x == 0) {
        float v = loss_acc[0] * (1.0f/4194304.0f);
        o[0] = v;
        o[1] = v;
    }
}

extern "C" void kernel_launch(void* const* d_in, const int* in_sizes, int n_in,
                              void* d_out, int out_size, void* d_ws, size_t ws_size,
                              hipStream_t stream) {
    (void)in_sizes; (void)n_in; (void)out_size; (void)ws_size;
    const float* x   = (const float*)d_in[0];
    const float* ew1 = (const float*)d_in[1];
    const float* eb1 = (const float*)d_in[2];
    const float* ew2 = (const float*)d_in[3];
    const float* eb2 = (const float*)d_in[4];
    const float* ew3 = (const float*)d_in[5];
    const float* eb3 = (const float*)d_in[6];
    const float* cb  = (const float*)d_in[7];
    const float* dw1 = (const float*)d_in[8];
    const float* db1 = (const float*)d_in[9];
    const float* dw2 = (const float*)d_in[10];
    const float* db2 = (const float*)d_in[11];
    const float* dw3 = (const float*)d_in[12];
    const float* db3 = (const float*)d_in[13];

    float* ws = (float*)d_ws;
    unsigned short* h1h  = (unsigned short*)(ws);                 // 33,554,432 us
    unsigned short* h1l  = (unsigned short*)(ws + 16777216);      // 33,554,432 us
    float*          h2   = ws + 33554432;                         //  8,388,608 f
    float*          ze   = ws + 41943040;                         //  4,194,304 f
    unsigned short* zqb  = (unsigned short*)(ws + 46137344);      //  4,194,304 us
    unsigned short* we2h = (unsigned short*)(ws + 48234496);      //    262,144 us
    unsigned short* we2l = (unsigned short*)(ws + 48365568);      //    262,144 us
    unsigned short* wd2b = (unsigned short*)(ws + 48496640);      //    262,144 us
    unsigned short* wd1b = (unsigned short*)(ws + 48627712);      //    131,072 us
    float*          lacc = ws + 48693248;                         //          1 f
    float*          zsc  = ws + 48693252;                         //  4 f (16B zeros)
    unsigned short* g1b  = h1h;   // reuse (dead after conv2m)

    float* xrec = (float*)d_out;            // 3,145,728 f
    float* tokf = xrec + 3145728;           //    65,536 f
    float* loss = tokf + 65536;             //         2 f

    k_zero    <<<   1,  64, 0, stream>>>(lacc, zsc);
    k_wsplit2 <<<1024, 256, 0, stream>>>(ew2, we2h, we2l);
    k_wcvt2   <<<1024, 256, 0, stream>>>(dw2, wd2b);
    k_wcvt1   <<< 512, 256, 0, stream>>>(dw1, wd1b);
    k_conv1   <<<4096, 256, 0, stream>>>(x, ew1, eb1, h1h, h1l);
    k_conv2m  <<< 512, 512, 0, stream>>>(h1h, h1l, we2h, we2l, eb2, zsc, h2);
    k_conv3   <<< 512, 256, 0, stream>>>(h2, ew3, eb3, ze);
    k_vq      <<<1024, 256, 0, stream>>>(ze, cb, zqb, tokf, lacc);
    k_convt1m <<<4096, 256, 0, stream>>>(zqb, wd1b, db1, zsc, g1b);
    k_convt2  <<<8192, 256, 0, stream>>>(g1b, wd2b, db2, dw3, db3, zsc, xrec);
    k_finalize<<<   1,  64, 0, stream>>>(lacc, loss);
}

// Round 9
// 837.661 us; speedup vs baseline: 1.3250x; 1.3250x over previous
//
#include <hip/hip_runtime.h>
#include <math.h>

// Shapes: B=16, x[16,256,256,3], h1[16,128,128,128], h2[16,64,64,128],
// z_e/z_q[65536,64], g1[16,128,128,128](bf16), x_rec[16,256,256,3], K=1024.
//
// R9: revert R8's quarter-major layout (it scattered the async16 global reads
// into 64 cache-lines/instr -> drains ballooned). convt2 = R5's 4-phase
// structure (287us best) + shuffle epilogue + XCD swizzle + NEW hoisted
// incremental staging pointers (kc loop only bumps pointers, no re-decode).
// conv2m = R7 512-thr; convt1m/conv1/conv3/vq = R6.

typedef __attribute__((ext_vector_type(8))) short short8;
typedef __attribute__((ext_vector_type(4))) float f32x4;

__device__ __forceinline__ float gelu_f(float x) {          // encoder (exact path)
    float x3 = x*x*x;
    return 0.5f*x*(1.0f + tanhf(0.7978845608028654f*(x + 0.044715f*x3)));
}
__device__ __forceinline__ float gelu_fast(float x) {       // decoder only
    float t = __expf(-1.5957691216057308f*(x + 0.044715f*x*x*x));
    return x / (1.f + t);
}

__device__ __forceinline__ unsigned short f2bf(float f) {
    unsigned int u = __float_as_uint(f);
    u = (u + 0x7FFFu + ((u >> 16) & 1u)) >> 16;   // RNE
    return (unsigned short)u;
}
__device__ __forceinline__ float bf2f(unsigned short h) {
    return __uint_as_float(((unsigned int)h) << 16);
}

typedef const __attribute__((address_space(1))) unsigned int* gp_t;
typedef __attribute__((address_space(3))) unsigned int* lp_t;
__device__ __forceinline__ void async16(const void* g, void* l) {
    __builtin_amdgcn_global_load_lds((gp_t)g, (lp_t)l, 16, 0, 0);
}

// ---------------- conv1: x[16,256,256,3] -> h1 hi/lo bf16 planes, 4x4 s2 SAME, GELU
__global__ __launch_bounds__(256) void k_conv1(const float* __restrict__ x,
        const float* __restrict__ w, const float* __restrict__ bias,
        unsigned short* __restrict__ outh, unsigned short* __restrict__ outl) {
    __shared__ __align__(16) float ws[48*128];
    __shared__ __align__(16) float xs[4][390];
    const int tid = threadIdx.x;
    const int blk = blockIdx.x;
    const int oxt = blk & 1;
    const int oy  = (blk >> 1) & 127;
    const int b   = blk >> 8;
    const int cg = tid & 15, pg = tid >> 4;
    const int c0a = cg*4, c0b = 64 + cg*4;
    const int p0 = pg*4;
    const int ox0 = oxt*64;

    for (int i = tid; i < 6144; i += 256) ws[i] = w[i];
    for (int r = 0; r < 4; ++r) {
        int iy = 2*oy + r - 1;
        bool yok = (unsigned)iy < 256u;
        const float* xrow = x + ((size_t)(b*256) + iy)*256*3;
        for (int i = tid; i < 390; i += 256) {
            int ixl = i/3, ci = i - ixl*3;
            int ix = 2*ox0 - 1 + ixl;
            xs[r][i] = (yok && (unsigned)ix < 256u) ? xrow[(size_t)ix*3 + ci] : 0.f;
        }
    }
    __syncthreads();

    float acc[4][8];
    #pragma unroll
    for (int j = 0; j < 4; ++j)
        #pragma unroll
        for (int i = 0; i < 8; ++i) acc[j][i] = 0.f;

    #pragma unroll 6
    for (int pos = 0; pos < 48; ++pos) {
        int r = pos/12, tc = pos - r*12;
        int t = tc/3,  ci = tc - t*3;
        float4 w0 = *(const float4*)&ws[pos*128 + c0a];
        float4 w1 = *(const float4*)&ws[pos*128 + c0b];
        #pragma unroll
        for (int j = 0; j < 4; ++j) {
            float av = xs[r][(2*(p0+j) + t)*3 + ci];
            acc[j][0] += av*w0.x; acc[j][1] += av*w0.y;
            acc[j][2] += av*w0.z; acc[j][3] += av*w0.w;
            acc[j][4] += av*w1.x; acc[j][5] += av*w1.y;
            acc[j][6] += av*w1.z; acc[j][7] += av*w1.w;
        }
    }
    float bv[8];
    #pragma unroll
    for (int i = 0; i < 4; ++i) { bv[i] = bias[c0a+i]; bv[4+i] = bias[c0b+i]; }
    #pragma unroll
    for (int j = 0; j < 4; ++j) {
        int ox = ox0 + p0 + j;
        size_t base = (((size_t)(b*128) + oy)*128 + ox)*128;
        ushort4 ha, hb, la, lb;
        float y;
        y = gelu_f(acc[j][0]+bv[0]); ha.x = f2bf(y); la.x = f2bf(y - bf2f(ha.x));
        y = gelu_f(acc[j][1]+bv[1]); ha.y = f2bf(y); la.y = f2bf(y - bf2f(ha.y));
        y = gelu_f(acc[j][2]+bv[2]); ha.z = f2bf(y); la.z = f2bf(y - bf2f(ha.z));
        y = gelu_f(acc[j][3]+bv[3]); ha.w = f2bf(y); la.w = f2bf(y - bf2f(ha.w));
        y = gelu_f(acc[j][4]+bv[4]); hb.x = f2bf(y); lb.x = f2bf(y - bf2f(hb.x));
        y = gelu_f(acc[j][5]+bv[5]); hb.y = f2bf(y); lb.y = f2bf(y - bf2f(hb.y));
        y = gelu_f(acc[j][6]+bv[6]); hb.z = f2bf(y); lb.z = f2bf(y - bf2f(hb.z));
        y = gelu_f(acc[j][7]+bv[7]); hb.w = f2bf(y); lb.w = f2bf(y - bf2f(hb.w));
        *(ushort4*)&outh[base + c0a] = ha;
        *(ushort4*)&outh[base + c0b] = hb;
        *(ushort4*)&outl[base + c0a] = la;
        *(ushort4*)&outl[base + c0b] = lb;
    }
}

// ---------------- conv2 (split-bf16 MFMA, async16, 512 thr): h1 -> h2 f32, GELU
// Block (b, oy-pair): M=128 px, N=128 co. 8 waves 4Mx2N, wave tile 32x64.
__global__ __launch_bounds__(512) void k_conv2m(const unsigned short* __restrict__ h1h,
        const unsigned short* __restrict__ h1l,
        const unsigned short* __restrict__ w2h, const unsigned short* __restrict__ w2l,
        const float* __restrict__ bias, const float* __restrict__ zsc,
        float* __restrict__ out) {
    __shared__ __align__(16) unsigned short Ah[2*128*32];
    __shared__ __align__(16) unsigned short Al[2*128*32];
    __shared__ __align__(16) unsigned short Bh[2*128*32];
    __shared__ __align__(16) unsigned short Bl[2*128*32];
    const int tid = threadIdx.x;
    const int yy = blockIdx.x & 31;
    const int b  = blockIdx.x >> 5;
    const int oy0 = yy*2;
    const int lane = tid & 63, l15 = lane & 15, q = lane >> 4;
    const int wid = tid >> 6;                  // 0..7
    const int wm = wid >> 1, wn = wid & 1;     // wave tile 32x64
    const int psub = lane >> 2;
    const int csub = (lane & 3) * 8;

    f32x4 acc[2][4];
    #pragma unroll
    for (int fm = 0; fm < 2; ++fm)
        #pragma unroll
        for (int fn = 0; fn < 4; ++fn) acc[fm][fn] = (f32x4){0.f,0.f,0.f,0.f};

    for (int tap = 0; tap < 16; ++tap) {
        int r = tap >> 2, t = tap & 3;
        for (int cs = 0; cs < 2; ++cs) {
            __syncthreads();
            #pragma unroll
            for (int j = 0; j < 8; ++j) {
                int id = wid*8 + j;           // 0..63, wave-uniform
                int plane = id >> 4;          // 0 Ah, 1 Al, 2 Bh, 3 Bl
                int kc_ = (id >> 3) & 1, s2 = id & 7;
                int ci = cs*64 + kc_*32 + csub;
                if (plane < 2) {
                    int px = s2*16 + psub;
                    int oyv = oy0 + (px >> 6), ox = px & 63;
                    int iy = 2*oyv + r - 1, ix = 2*ox + t - 1;
                    bool ok = (unsigned)iy < 128u && (unsigned)ix < 128u;
                    const unsigned short* base = plane ? h1l : h1h;
                    const unsigned short* gp = ok
                        ? base + (((size_t)(b*128)+iy)*128+ix)*128 + ci
                        : (const unsigned short*)zsc;
                    async16(gp, (plane ? Al : Ah) + (kc_*128 + s2*16)*32);
                } else {
                    int co = s2*16 + psub;
                    const unsigned short* base = (plane == 3) ? w2l : w2h;
                    async16(base + ((size_t)tap*128 + co)*128 + ci,
                            ((plane == 3) ? Bl : Bh) + (kc_*128 + s2*16)*32);
                }
            }
            __syncthreads();
            #pragma unroll
            for (int kc = 0; kc < 2; ++kc) {
                short8 ah[2], al[2], bh[4], bl[4];
                #pragma unroll
                for (int fm = 0; fm < 2; ++fm) {
                    int row = (kc*128 + wm*32 + fm*16 + l15)*32 + q*8;
                    ah[fm] = *(const short8*)&Ah[row];
                    al[fm] = *(const short8*)&Al[row];
                }
                #pragma unroll
                for (int fn = 0; fn < 4; ++fn) {
                    int row = (kc*128 + wn*64 + fn*16 + l15)*32 + q*8;
                    bh[fn] = *(const short8*)&Bh[row];
                    bl[fn] = *(const short8*)&Bl[row];
                }
                #pragma unroll
                for (int fm = 0; fm < 2; ++fm)
                    #pragma unroll
                    for (int fn = 0; fn < 4; ++fn) {
                        acc[fm][fn] = __builtin_amdgcn_mfma_f32_16x16x32_bf16(
                            ah[fm], bh[fn], acc[fm][fn], 0, 0, 0);
                        acc[fm][fn] = __builtin_amdgcn_mfma_f32_16x16x32_bf16(
                            al[fm], bh[fn], acc[fm][fn], 0, 0, 0);
                        acc[fm][fn] = __builtin_amdgcn_mfma_f32_16x16x32_bf16(
                            ah[fm], bl[fn], acc[fm][fn], 0, 0, 0);
                    }
            }
        }
    }
    float bv[4];
    #pragma unroll
    for (int fn = 0; fn < 4; ++fn) bv[fn] = bias[wn*64 + fn*16 + l15];
    #pragma unroll
    for (int fm = 0; fm < 2; ++fm)
        #pragma unroll
        for (int rg = 0; rg < 4; ++rg) {
            int px = wm*32 + fm*16 + q*4 + rg;
            int oy = oy0 + (px >> 6), ox = px & 63;
            float* o = out + (((size_t)(b*64) + oy)*64 + ox)*128;
            #pragma unroll
            for (int fn = 0; fn < 4; ++fn)
                o[wn*64 + fn*16 + l15] = gelu_f(acc[fm][fn][rg] + bv[fn]);
        }
}

// ---------------- conv3 (1x1, 128->64, f32): h2 -> z_e [65536,64]
__global__ __launch_bounds__(256) void k_conv3(const float* __restrict__ in,
        const float* __restrict__ w, const float* __restrict__ bias,
        float* __restrict__ out) {
    __shared__ __align__(16) float xs[128*33];
    __shared__ __align__(16) float wb[32*64];
    const int tid = threadIdx.x;
    const size_t pix0 = (size_t)blockIdx.x * 128;
    const int cg = tid & 7, pg = tid >> 3;
    const int c0a = cg*4, c0b = 32 + cg*4;
    const int p0 = pg*4;

    float acc[4][8];
    #pragma unroll
    for (int j = 0; j < 4; ++j)
        #pragma unroll
        for (int i = 0; i < 8; ++i) acc[j][i] = 0.f;

    for (int cs = 0; cs < 4; ++cs) {
        __syncthreads();
        for (int i = tid; i < 4096; i += 256) {
            int p = i >> 5, ci = i & 31;
            xs[p*33 + ci] = in[(pix0 + p)*128 + cs*32 + ci];
        }
        for (int i = tid; i < 2048; i += 256) {
            int ci = i >> 6, c = i & 63;
            wb[i] = w[(size_t)(cs*32 + ci)*64 + c];
        }
        __syncthreads();
        #pragma unroll 8
        for (int ci = 0; ci < 32; ++ci) {
            float a_[4];
            #pragma unroll
            for (int j = 0; j < 4; ++j) a_[j] = xs[(p0+j)*33 + ci];
            float4 b0 = *(const float4*)&wb[ci*64 + c0a];
            float4 b1 = *(const float4*)&wb[ci*64 + c0b];
            #pragma unroll
            for (int j = 0; j < 4; ++j) {
                acc[j][0] += a_[j]*b0.x; acc[j][1] += a_[j]*b0.y;
                acc[j][2] += a_[j]*b0.z; acc[j][3] += a_[j]*b0.w;
                acc[j][4] += a_[j]*b1.x; acc[j][5] += a_[j]*b1.y;
                acc[j][6] += a_[j]*b1.z; acc[j][7] += a_[j]*b1.w;
            }
        }
    }
    #pragma unroll
    for (int j = 0; j < 4; ++j) {
        float* o = out + (pix0 + p0 + j)*64;
        float4 va, vb;
        va.x = acc[j][0]+bias[c0a+0]; va.y = acc[j][1]+bias[c0a+1];
        va.z = acc[j][2]+bias[c0a+2]; va.w = acc[j][3]+bias[c0a+3];
        vb.x = acc[j][4]+bias[c0b+0]; vb.y = acc[j][5]+bias[c0b+1];
        vb.z = acc[j][6]+bias[c0b+2]; vb.w = acc[j][7]+bias[c0b+3];
        *(float4*)&o[c0a] = va;
        *(float4*)&o[c0b] = vb;
    }
}

// ---------------- VQ: f32 (exact), writes z_q as bf16 for the decoder
__global__ __launch_bounds__(256) void k_vq(const float* __restrict__ ze,
        const float* __restrict__ cb, unsigned short* __restrict__ zqb,
        float* __restrict__ tok, float* __restrict__ loss_acc) {
    __shared__ __align__(16) float zs[64*65];
    __shared__ __align__(16) float bt[64*132];
    __shared__ float es[128];
    __shared__ float z2s[64];
    __shared__ float rmin[64*16];
    __shared__ int   ridx[64*16];
    __shared__ int   widx[64];
    __shared__ float wsum[4];
    const int tid = threadIdx.x;
    const size_t tok0 = (size_t)blockIdx.x * 64;
    const int cg = tid & 15, pg = tid >> 4;
    const int k0a = cg*4, k0b = 64 + cg*4;
    const int t0 = pg*4;

    for (int i = tid; i < 4096; i += 256) {
        int tk = i >> 6, d = i & 63;
        zs[tk*65 + d] = ze[(tok0 + tk)*64 + d];
    }
    __syncthreads();
    if (tid < 64) {
        float s = 0.f;
        for (int d = 0; d < 64; ++d) { float v = zs[tid*65 + d]; s += v*v; }
        z2s[tid] = s;
    }

    float bmin[4] = {3.4e38f,3.4e38f,3.4e38f,3.4e38f};
    int   bidx[4] = {0,0,0,0};

    for (int ch = 0; ch < 8; ++ch) {
        __syncthreads();
        for (int i = tid; i < 8192; i += 256) {
            int k = i >> 6, d = i & 63;
            bt[d*132 + k] = cb[((size_t)(ch*128) + k)*64 + d];
        }
        __syncthreads();
        if (tid < 128) {
            float s = 0.f;
            for (int d = 0; d < 64; ++d) { float v = bt[d*132 + tid]; s += v*v; }
            es[tid] = s;
        }
        __syncthreads();
        float acc[4][8];
        #pragma unroll
        for (int j = 0; j < 4; ++j)
            #pragma unroll
            for (int i = 0; i < 8; ++i) acc[j][i] = 0.f;
        #pragma unroll 4
        for (int d = 0; d < 64; ++d) {
            float a_[4];
            #pragma unroll
            for (int j = 0; j < 4; ++j) a_[j] = zs[(t0+j)*65 + d];
            float4 b0 = *(const float4*)&bt[d*132 + k0a];
            float4 b1 = *(const float4*)&bt[d*132 + k0b];
            #pragma unroll
            for (int j = 0; j < 4; ++j) {
                acc[j][0] += a_[j]*b0.x; acc[j][1] += a_[j]*b0.y;
                acc[j][2] += a_[j]*b0.z; acc[j][3] += a_[j]*b0.w;
                acc[j][4] += a_[j]*b1.x; acc[j][5] += a_[j]*b1.y;
                acc[j][6] += a_[j]*b1.z; acc[j][7] += a_[j]*b1.w;
            }
        }
        #pragma unroll
        for (int j = 0; j < 4; ++j) {
            float z2 = z2s[t0+j];
            #pragma unroll
            for (int i = 0; i < 4; ++i) {
                float dist = (z2 + es[k0a+i]) - 2.f*acc[j][i];
                int idx = ch*128 + k0a + i;
                if (dist < bmin[j]) { bmin[j] = dist; bidx[j] = idx; }
            }
            #pragma unroll
            for (int i = 0; i < 4; ++i) {
                float dist = (z2 + es[k0b+i]) - 2.f*acc[j][4+i];
                int idx = ch*128 + k0b + i;
                if (dist < bmin[j]) { bmin[j] = dist; bidx[j] = idx; }
            }
        }
    }
    #pragma unroll
    for (int j = 0; j < 4; ++j) {
        rmin[(t0+j)*16 + cg] = bmin[j];
        ridx[(t0+j)*16 + cg] = bidx[j];
    }
    __syncthreads();
    if (tid < 64) {
        float bv = rmin[tid*16]; int bi = ridx[tid*16];
        for (int g = 1; g < 16; ++g) {
            float v = rmin[tid*16 + g]; int ii = ridx[tid*16 + g];
            if (v < bv || (v == bv && ii < bi)) { bv = v; bi = ii; }
        }
        widx[tid] = bi;
        tok[tok0 + tid] = (float)bi;
    }
    __syncthreads();
    float lsum = 0.f;
    for (int i = tid; i < 4096; i += 256) {
        int tk = i >> 6, d = i & 63;
        float v = cb[(size_t)widx[tk]*64 + d];
        zqb[(tok0 + tk)*64 + d] = f2bf(v);
        float diff = v - zs[tk*65 + d];
        lsum += diff*diff;
    }
    #pragma unroll
    for (int off = 32; off > 0; off >>= 1) lsum += __shfl_down(lsum, off, 64);
    if ((tid & 63) == 0) wsum[tid >> 6] = lsum;
    __syncthreads();
    if (tid == 0) atomicAdd(loss_acc, wsum[0]+wsum[1]+wsum[2]+wsum[3]);
}

// ---------------- weight prep kernels
__global__ __launch_bounds__(256) void k_wsplit2(const float* __restrict__ w,
        unsigned short* __restrict__ hi, unsigned short* __restrict__ lo) {
    int i = blockIdx.x*256 + threadIdx.x;        // 262144
    int rt = i >> 14, rem = i & 16383;
    int co = rem >> 7, ci = rem & 127;
    float v = w[((size_t)rt*128 + ci)*128 + co];
    unsigned short h = f2bf(v);
    hi[i] = h;
    lo[i] = f2bf(v - bf2f(h));
}
__global__ __launch_bounds__(256) void k_wcvt2(const float* __restrict__ w,
        unsigned short* __restrict__ o) {
    int i = blockIdx.x*256 + threadIdx.x;        // 262144
    int rt = i >> 14, rem = i & 16383;
    int co = rem >> 7, ci = rem & 127;
    o[i] = f2bf(w[((size_t)rt*128 + ci)*128 + co]);
}
__global__ __launch_bounds__(256) void k_wcvt1(const float* __restrict__ w,
        unsigned short* __restrict__ o) {
    int i = blockIdx.x*256 + threadIdx.x;        // 131072
    int rt = i >> 13, rem = i & 8191;
    int co = rem >> 6, ci = rem & 63;
    o[i] = f2bf(w[((size_t)rt*64 + ci)*128 + co]);
}

// ---------------- convT1 (bf16 MFMA, async16 staging): zqb -> g1b bf16, GELU
__global__ __launch_bounds__(256) void k_convt1m(const unsigned short* __restrict__ zqb,
        const unsigned short* __restrict__ w1b, const float* __restrict__ bias,
        const float* __restrict__ zsc, unsigned short* __restrict__ out) {
    __shared__ __align__(16) unsigned short A[2*128*32];
    __shared__ __align__(16) unsigned short Bm[2*128*32];
    const int tid = threadIdx.x;
    const int par = blockIdx.x & 1;
    const int ey  = (blockIdx.x >> 1) & 1;
    const int qq  = (blockIdx.x >> 2) & 31;
    const int b   = blockIdx.x >> 7;
    const int q0  = qq*2;
    const int lane = tid & 63, l15 = lane & 15, q = lane >> 4;
    const int wid = tid >> 6, wm = wid >> 1, wn = wid & 1;
    const int psub = lane >> 2;
    const int csub = (lane & 3) * 8;

    f32x4 acc[4][4];
    #pragma unroll
    for (int fm = 0; fm < 4; ++fm)
        #pragma unroll
        for (int fn = 0; fn < 4; ++fn) acc[fm][fn] = (f32x4){0.f,0.f,0.f,0.f};

    for (int tap = 0; tap < 4; ++tap) {
        int rr = tap >> 1, tt = tap & 1;
        int rt = (ey + 2*rr)*4 + (par + 2*tt);
        __syncthreads();
        #pragma unroll
        for (int j = 0; j < 8; ++j) {
            int id = wid*8 + j;               // 0..31, wave-uniform
            int kc = (id >> 3) & 1, s2 = id & 7;
            int ci = kc*32 + csub;
            if (id < 16) {
                int px = s2*16 + psub;
                int qv = q0 + (px >> 6), p = px & 63;
                int iy = qv + ey - 1 + rr, ix = p + par - 1 + tt;
                bool ok = (unsigned)iy < 64u && (unsigned)ix < 64u;
                const unsigned short* gp = ok
                    ? zqb + (((size_t)(b*64)+iy)*64+ix)*64 + ci
                    : (const unsigned short*)zsc;
                async16(gp, A + (kc*128 + s2*16)*32);
            } else {
                int co = s2*16 + psub;
                async16(w1b + ((size_t)rt*128 + co)*64 + ci,
                        Bm + (kc*128 + s2*16)*32);
            }
        }
        __syncthreads();
        #pragma unroll
        for (int kc = 0; kc < 2; ++kc) {
            short8 af[4], bf[4];
            #pragma unroll
            for (int fm = 0; fm < 4; ++fm)
                af[fm] = *(const short8*)&A[(kc*128 + wm*64 + fm*16 + l15)*32 + q*8];
            #pragma unroll
            for (int fn = 0; fn < 4; ++fn)
                bf[fn] = *(const short8*)&Bm[(kc*128 + wn*64 + fn*16 + l15)*32 + q*8];
            #pragma unroll
            for (int fm = 0; fm < 4; ++fm)
                #pragma unroll
                for (int fn = 0; fn < 4; ++fn)
                    acc[fm][fn] = __builtin_amdgcn_mfma_f32_16x16x32_bf16(
                        af[fm], bf[fn], acc[fm][fn], 0, 0, 0);
        }
    }
    float bv[4];
    #pragma unroll
    for (int fn = 0; fn < 4; ++fn) bv[fn] = bias[wn*64 + fn*16 + l15];
    #pragma unroll
    for (int fm = 0; fm < 4; ++fm)
        #pragma unroll
        for (int rg = 0; rg < 4; ++rg) {
            int px = wm*64 + fm*16 + q*4 + rg;
            int qv = q0 + (px >> 6), p = px & 63;
            int oy = 2*qv + ey, ox = par + 2*p;
            unsigned short* o = out + (((size_t)(b*128) + oy)*128 + ox)*128;
            #pragma unroll
            for (int fn = 0; fn < 4; ++fn)
                o[wn*64 + fn*16 + l15] = f2bf(gelu_fast(acc[fm][fn][rg] + bv[fn]));
        }
}

// ---------------- convT2 (bf16 MFMA, R5 4-phase structure, hoisted pointers)
// Block (b,oy,par): M=128 px, N=128 co, K=4 taps x 128 ci (chunked by 32 ci).
// LDS: Araw[2 rows][130 cols(+halo)][32 ci] + B4[4 taps][128 co][32 ci].
__global__ __launch_bounds__(256) void k_convt2(const unsigned short* __restrict__ g1b,
        const unsigned short* __restrict__ wtb, const float* __restrict__ b2,
        const float* __restrict__ w3, const float* __restrict__ b3,
        const float* __restrict__ zsc, float* __restrict__ xrec) {
    union SM {
        struct {
            unsigned short Araw[2*130*32];   // 16640 B
            unsigned short B4[4*128*32];     // 32768 B
        } s;
        float red[128*2*3];                  // 3072 B
    };
    __shared__ __align__(16) union SM sm;
    const int tid = threadIdx.x;
    // XCD swizzle: consecutive same-XCD blocks walk par, then qy (L2 row reuse)
    const int gblk = blockIdx.x;
    const int xcd = gblk & 7;
    const int s_  = gblk >> 3;                 // 0..1023
    const int par = s_ & 1;
    const int qy  = (s_ >> 1) & 127;
    const int ey  = (s_ >> 8) & 1;
    const int b   = xcd*2 + (s_ >> 9);
    const int oy  = qy*2 + ey;
    const int lane = tid & 63, l15 = lane & 15, q = lane >> 4;
    const int wid = tid >> 6, wm = wid >> 1, wn = wid & 1;
    const int iy0 = qy + ey - 1;
    const int psub = lane >> 2;
    const int csub = (lane & 3) * 8;

    f32x4 acc[4][4];
    #pragma unroll
    for (int fm = 0; fm < 4; ++fm)
        #pragma unroll
        for (int fn = 0; fn < 4; ++fn) acc[fm][fn] = (f32x4){0.f,0.f,0.f,0.f};

    // zero halo columns (raw cols -1 and 128 -> lds cols 0 and 129)
    if (tid < 16) {
        int rr = tid >> 3, side = (tid >> 2) & 1, qtr = tid & 3;
        int col = side ? 129 : 0;
        *(uint4*)&sm.s.Araw[(rr*130 + col)*32 + qtr*8] = make_uint4(0,0,0,0);
    }

    // ---- hoisted staging descriptors (computed once; kc loop only bumps) ----
    // A: 4 slots/thread. seg = wid*4+j: rr = seg>>3, s = seg&7.
    const unsigned short* aptr[4];
    int astep[4];
    unsigned int aldst[4];
    #pragma unroll
    for (int j = 0; j < 4; ++j) {
        int seg = wid*4 + j;
        int rr = seg >> 3, s = seg & 7;
        int iy = iy0 + rr;
        bool yok = (unsigned)iy < 128u;
        aptr[j] = yok
            ? g1b + (((size_t)(b*128) + iy)*128 + s*16 + psub)*128 + csub
            : (const unsigned short*)zsc;
        astep[j] = yok ? 32 : 0;
        aldst[j] = (unsigned)((rr*130 + s*16 + 1)*32);
    }
    // B: 8 slots/thread. seg = wid*8+j: tap = seg>>3, s = seg&7.
    const unsigned short* bptr[8];
    unsigned int bldst[8];
    #pragma unroll
    for (int j = 0; j < 8; ++j) {
        int seg = wid*8 + j;
        int tap = seg >> 3, s = seg & 7;
        int rr = tap >> 1, tt = tap & 1;
        int rt = (ey + 2*rr)*4 + (par + 2*tt);
        bptr[j] = wtb + ((size_t)rt*128 + s*16 + psub)*128 + csub;
        bldst[j] = (unsigned)((tap*128 + s*16)*32);
    }

    for (int kc = 0; kc < 4; ++kc) {
        __syncthreads();   // protect prior chunk's reads (and halo zeros, 1st)
        #pragma unroll
        for (int j = 0; j < 4; ++j) {
            async16(aptr[j], &sm.s.Araw[aldst[j]]);
            aptr[j] += astep[j];
        }
        #pragma unroll
        for (int j = 0; j < 8; ++j) {
            async16(bptr[j], &sm.s.B4[bldst[j]]);
            bptr[j] += 32;
        }
        __syncthreads();   // drain (compiler emits vmcnt(0))
        #pragma unroll
        for (int tap = 0; tap < 4; ++tap) {
            int rr = tap >> 1, tt = tap & 1;
            short8 af[4], bf[4];
            #pragma unroll
            for (int fm = 0; fm < 4; ++fm)
                af[fm] = *(const short8*)&sm.s.Araw[
                    (rr*130 + wm*64 + fm*16 + l15 + par + tt)*32 + q*8];
            #pragma unroll
            for (int fn = 0; fn < 4; ++fn)
                bf[fn] = *(const short8*)&sm.s.B4[
                    (tap*128 + wn*64 + fn*16 + l15)*32 + q*8];
            #pragma unroll
            for (int fm = 0; fm < 4; ++fm)
                #pragma unroll
                for (int fn = 0; fn < 4; ++fn)
                    acc[fm][fn] = __builtin_amdgcn_mfma_f32_16x16x32_bf16(
                        af[fm], bf[fn], acc[fm][fn], 0, 0, 0);
        }
    }

    // epilogue: GELU(acc+b2), project 128->3, shuffle-reduce over l15 (co dim)
    float b2v[4];
    float w3v[4][3];
    #pragma unroll
    for (int fn = 0; fn < 4; ++fn) {
        int co = wn*64 + fn*16 + l15;
        b2v[fn] = b2[co];
        w3v[fn][0] = w3[co*3+0]; w3v[fn][1] = w3[co*3+1]; w3v[fn][2] = w3[co*3+2];
    }
    __syncthreads();
    #pragma unroll
    for (int fm = 0; fm < 4; ++fm) {
        #pragma unroll
        for (int rg = 0; rg < 4; ++rg) {
            float s0 = 0.f, s1 = 0.f, s2 = 0.f;
            #pragma unroll
            for (int fn = 0; fn < 4; ++fn) {
                float y = gelu_fast(acc[fm][fn][rg] + b2v[fn]);
                s0 += y*w3v[fn][0]; s1 += y*w3v[fn][1]; s2 += y*w3v[fn][2];
            }
            #pragma unroll
            for (int m = 1; m < 16; m <<= 1) {
                s0 += __shfl_xor(s0, m, 64);
                s1 += __shfl_xor(s1, m, 64);
                s2 += __shfl_xor(s2, m, 64);
            }
            if (l15 == 0) {
                int px = wm*64 + fm*16 + q*4 + rg;
                sm.red[(px*2 + wn)*3 + 0] = s0;
                sm.red[(px*2 + wn)*3 + 1] = s1;
                sm.red[(px*2 + wn)*3 + 2] = s2;
            }
        }
    }
    __syncthreads();
    for (int o = tid; o < 384; o += 256) {
        int px = o/3, jj = o - px*3;
        float s = b3[jj] + sm.red[(px*2 + 0)*3 + jj] + sm.red[(px*2 + 1)*3 + jj];
        xrec[(((size_t)(b*256) + oy)*256 + (par + 2*px))*3 + jj] = s;
    }
}

__global__ void k_zero(float* lacc, float* zsc) {
    if (threadIdx.x == 0) lacc[0] = 0.f;
    if (threadIdx.x < 4) zsc[threadIdx.x] = 0.f;
}

__global__ void k_finalize(const float* __restrict__ loss_acc, float* __restrict__ o) {
    if (threadIdx.x == 0) {
        float v = loss_acc[0] * (1.0f/4194304.0f);
        o[0] = v;
        o[1] = v;
    }
}

extern "C" void kernel_launch(void* const* d_in, const int* in_sizes, int n_in,
                              void* d_out, int out_size, void* d_ws, size_t ws_size,
                              hipStream_t stream) {
    (void)in_sizes; (void)n_in; (void)out_size; (void)ws_size;
    const float* x   = (const float*)d_in[0];
    const float* ew1 = (const float*)d_in[1];
    const float* eb1 = (const float*)d_in[2];
    const float* ew2 = (const float*)d_in[3];
    const float* eb2 = (const float*)d_in[4];
    const float* ew3 = (const float*)d_in[5];
    const float* eb3 = (const float*)d_in[6];
    const float* cb  = (const float*)d_in[7];
    const float* dw1 = (const float*)d_in[8];
    const float* db1 = (const float*)d_in[9];
    const float* dw2 = (const float*)d_in[10];
    const float* db2 = (const float*)d_in[11];
    const float* dw3 = (const float*)d_in[12];
    const float* db3 = (const float*)d_in[13];

    float* ws = (float*)d_ws;
    unsigned short* h1h  = (unsigned short*)(ws);                 // 33,554,432 us
    unsigned short* h1l  = (unsigned short*)(ws + 16777216);      // 33,554,432 us
    float*          h2   = ws + 33554432;                         //  8,388,608 f
    float*          ze   = ws + 41943040;                         //  4,194,304 f
    unsigned short* zqb  = (unsigned short*)(ws + 46137344);      //  4,194,304 us
    unsigned short* we2h = (unsigned short*)(ws + 48234496);      //    262,144 us
    unsigned short* we2l = (unsigned short*)(ws + 48365568);      //    262,144 us
    unsigned short* wd2b = (unsigned short*)(ws + 48496640);      //    262,144 us
    unsigned short* wd1b = (unsigned short*)(ws + 48627712);      //    131,072 us
    float*          lacc = ws + 48693248;                         //          1 f
    float*          zsc  = ws + 48693252;                         //  4 f (16B zeros)
    unsigned short* g1b  = h1h;   // reuse (dead after conv2m)

    float* xrec = (float*)d_out;            // 3,145,728 f
    float* tokf = xrec + 3145728;           //    65,536 f
    float* loss = tokf + 65536;             //         2 f

    k_zero    <<<   1,  64, 0, stream>>>(lacc, zsc);
    k_wsplit2 <<<1024, 256, 0, stream>>>(ew2, we2h, we2l);
    k_wcvt2   <<<1024, 256, 0, stream>>>(dw2, wd2b);
    k_wcvt1   <<< 512, 256, 0, stream>>>(dw1, wd1b);
    k_conv1   <<<4096, 256, 0, stream>>>(x, ew1, eb1, h1h, h1l);
    k_conv2m  <<< 512, 512, 0, stream>>>(h1h, h1l, we2h, we2l, eb2, zsc, h2);
    k_conv3   <<< 512, 256, 0, stream>>>(h2, ew3, eb3, ze);
    k_vq      <<<1024, 256, 0, stream>>>(ze, cb, zqb, tokf, lacc);
    k_convt1m <<<4096, 256, 0, stream>>>(zqb, wd1b, db1, zsc, g1b);
    k_convt2  <<<8192, 256, 0, stream>>>(g1b, wd2b, db2, dw3, db3, zsc, xrec);
    k_finalize<<<   1,  64, 0, stream>>>(lacc, loss);
}

// Round 10
// 725.208 us; speedup vs baseline: 1.5305x; 1.1551x over previous
//
#include <hip/hip_runtime.h>
#include <math.h>

// Shapes: B=16, x[16,256,256,3], h1[16,128,128,128], h2[16,64,64,128],
// z_e/z_q[65536,64], g1[16,128,128,128](bf16), x_rec[16,256,256,3], K=1024.
//
// R10: convt2 -> M=256 over two ADJACENT qy rows (shared middle input row):
// 512 thr, 8 waves 4Mx2N, 3 A-rows + 4-tap B per kc phase, 8 barriers/block
// covering 2x output (staged bytes/output -40%, barriers/output -50%,
// 16 waves/CU vs 12). Everything else = R9.

typedef __attribute__((ext_vector_type(8))) short short8;
typedef __attribute__((ext_vector_type(4))) float f32x4;

__device__ __forceinline__ float gelu_f(float x) {          // encoder (exact path)
    float x3 = x*x*x;
    return 0.5f*x*(1.0f + tanhf(0.7978845608028654f*(x + 0.044715f*x3)));
}
__device__ __forceinline__ float gelu_fast(float x) {       // decoder only
    float t = __expf(-1.5957691216057308f*(x + 0.044715f*x*x*x));
    return x / (1.f + t);
}

__device__ __forceinline__ unsigned short f2bf(float f) {
    unsigned int u = __float_as_uint(f);
    u = (u + 0x7FFFu + ((u >> 16) & 1u)) >> 16;   // RNE
    return (unsigned short)u;
}
__device__ __forceinline__ float bf2f(unsigned short h) {
    return __uint_as_float(((unsigned int)h) << 16);
}

typedef const __attribute__((address_space(1))) unsigned int* gp_t;
typedef __attribute__((address_space(3))) unsigned int* lp_t;
__device__ __forceinline__ void async16(const void* g, void* l) {
    __builtin_amdgcn_global_load_lds((gp_t)g, (lp_t)l, 16, 0, 0);
}

// ---------------- conv1: x[16,256,256,3] -> h1 hi/lo bf16 planes, 4x4 s2 SAME, GELU
__global__ __launch_bounds__(256) void k_conv1(const float* __restrict__ x,
        const float* __restrict__ w, const float* __restrict__ bias,
        unsigned short* __restrict__ outh, unsigned short* __restrict__ outl) {
    __shared__ __align__(16) float ws[48*128];
    __shared__ __align__(16) float xs[4][390];
    const int tid = threadIdx.x;
    const int blk = blockIdx.x;
    const int oxt = blk & 1;
    const int oy  = (blk >> 1) & 127;
    const int b   = blk >> 8;
    const int cg = tid & 15, pg = tid >> 4;
    const int c0a = cg*4, c0b = 64 + cg*4;
    const int p0 = pg*4;
    const int ox0 = oxt*64;

    for (int i = tid; i < 6144; i += 256) ws[i] = w[i];
    for (int r = 0; r < 4; ++r) {
        int iy = 2*oy + r - 1;
        bool yok = (unsigned)iy < 256u;
        const float* xrow = x + ((size_t)(b*256) + iy)*256*3;
        for (int i = tid; i < 390; i += 256) {
            int ixl = i/3, ci = i - ixl*3;
            int ix = 2*ox0 - 1 + ixl;
            xs[r][i] = (yok && (unsigned)ix < 256u) ? xrow[(size_t)ix*3 + ci] : 0.f;
        }
    }
    __syncthreads();

    float acc[4][8];
    #pragma unroll
    for (int j = 0; j < 4; ++j)
        #pragma unroll
        for (int i = 0; i < 8; ++i) acc[j][i] = 0.f;

    #pragma unroll 6
    for (int pos = 0; pos < 48; ++pos) {
        int r = pos/12, tc = pos - r*12;
        int t = tc/3,  ci = tc - t*3;
        float4 w0 = *(const float4*)&ws[pos*128 + c0a];
        float4 w1 = *(const float4*)&ws[pos*128 + c0b];
        #pragma unroll
        for (int j = 0; j < 4; ++j) {
            float av = xs[r][(2*(p0+j) + t)*3 + ci];
            acc[j][0] += av*w0.x; acc[j][1] += av*w0.y;
            acc[j][2] += av*w0.z; acc[j][3] += av*w0.w;
            acc[j][4] += av*w1.x; acc[j][5] += av*w1.y;
            acc[j][6] += av*w1.z; acc[j][7] += av*w1.w;
        }
    }
    float bv[8];
    #pragma unroll
    for (int i = 0; i < 4; ++i) { bv[i] = bias[c0a+i]; bv[4+i] = bias[c0b+i]; }
    #pragma unroll
    for (int j = 0; j < 4; ++j) {
        int ox = ox0 + p0 + j;
        size_t base = (((size_t)(b*128) + oy)*128 + ox)*128;
        ushort4 ha, hb, la, lb;
        float y;
        y = gelu_f(acc[j][0]+bv[0]); ha.x = f2bf(y); la.x = f2bf(y - bf2f(ha.x));
        y = gelu_f(acc[j][1]+bv[1]); ha.y = f2bf(y); la.y = f2bf(y - bf2f(ha.y));
        y = gelu_f(acc[j][2]+bv[2]); ha.z = f2bf(y); la.z = f2bf(y - bf2f(ha.z));
        y = gelu_f(acc[j][3]+bv[3]); ha.w = f2bf(y); la.w = f2bf(y - bf2f(ha.w));
        y = gelu_f(acc[j][4]+bv[4]); hb.x = f2bf(y); lb.x = f2bf(y - bf2f(hb.x));
        y = gelu_f(acc[j][5]+bv[5]); hb.y = f2bf(y); lb.y = f2bf(y - bf2f(hb.y));
        y = gelu_f(acc[j][6]+bv[6]); hb.z = f2bf(y); lb.z = f2bf(y - bf2f(hb.z));
        y = gelu_f(acc[j][7]+bv[7]); hb.w = f2bf(y); lb.w = f2bf(y - bf2f(hb.w));
        *(ushort4*)&outh[base + c0a] = ha;
        *(ushort4*)&outh[base + c0b] = hb;
        *(ushort4*)&outl[base + c0a] = la;
        *(ushort4*)&outl[base + c0b] = lb;
    }
}

// ---------------- conv2 (split-bf16 MFMA, async16, 512 thr): h1 -> h2 f32, GELU
__global__ __launch_bounds__(512) void k_conv2m(const unsigned short* __restrict__ h1h,
        const unsigned short* __restrict__ h1l,
        const unsigned short* __restrict__ w2h, const unsigned short* __restrict__ w2l,
        const float* __restrict__ bias, const float* __restrict__ zsc,
        float* __restrict__ out) {
    __shared__ __align__(16) unsigned short Ah[2*128*32];
    __shared__ __align__(16) unsigned short Al[2*128*32];
    __shared__ __align__(16) unsigned short Bh[2*128*32];
    __shared__ __align__(16) unsigned short Bl[2*128*32];
    const int tid = threadIdx.x;
    const int yy = blockIdx.x & 31;
    const int b  = blockIdx.x >> 5;
    const int oy0 = yy*2;
    const int lane = tid & 63, l15 = lane & 15, q = lane >> 4;
    const int wid = tid >> 6;                  // 0..7
    const int wm = wid >> 1, wn = wid & 1;     // wave tile 32x64
    const int psub = lane >> 2;
    const int csub = (lane & 3) * 8;

    f32x4 acc[2][4];
    #pragma unroll
    for (int fm = 0; fm < 2; ++fm)
        #pragma unroll
        for (int fn = 0; fn < 4; ++fn) acc[fm][fn] = (f32x4){0.f,0.f,0.f,0.f};

    for (int tap = 0; tap < 16; ++tap) {
        int r = tap >> 2, t = tap & 3;
        for (int cs = 0; cs < 2; ++cs) {
            __syncthreads();
            #pragma unroll
            for (int j = 0; j < 8; ++j) {
                int id = wid*8 + j;           // 0..63, wave-uniform
                int plane = id >> 4;          // 0 Ah, 1 Al, 2 Bh, 3 Bl
                int kc_ = (id >> 3) & 1, s2 = id & 7;
                int ci = cs*64 + kc_*32 + csub;
                if (plane < 2) {
                    int px = s2*16 + psub;
                    int oyv = oy0 + (px >> 6), ox = px & 63;
                    int iy = 2*oyv + r - 1, ix = 2*ox + t - 1;
                    bool ok = (unsigned)iy < 128u && (unsigned)ix < 128u;
                    const unsigned short* base = plane ? h1l : h1h;
                    const unsigned short* gp = ok
                        ? base + (((size_t)(b*128)+iy)*128+ix)*128 + ci
                        : (const unsigned short*)zsc;
                    async16(gp, (plane ? Al : Ah) + (kc_*128 + s2*16)*32);
                } else {
                    int co = s2*16 + psub;
                    const unsigned short* base = (plane == 3) ? w2l : w2h;
                    async16(base + ((size_t)tap*128 + co)*128 + ci,
                            ((plane == 3) ? Bl : Bh) + (kc_*128 + s2*16)*32);
                }
            }
            __syncthreads();
            #pragma unroll
            for (int kc = 0; kc < 2; ++kc) {
                short8 ah[2], al[2], bh[4], bl[4];
                #pragma unroll
                for (int fm = 0; fm < 2; ++fm) {
                    int row = (kc*128 + wm*32 + fm*16 + l15)*32 + q*8;
                    ah[fm] = *(const short8*)&Ah[row];
                    al[fm] = *(const short8*)&Al[row];
                }
                #pragma unroll
                for (int fn = 0; fn < 4; ++fn) {
                    int row = (kc*128 + wn*64 + fn*16 + l15)*32 + q*8;
                    bh[fn] = *(const short8*)&Bh[row];
                    bl[fn] = *(const short8*)&Bl[row];
                }
                #pragma unroll
                for (int fm = 0; fm < 2; ++fm)
                    #pragma unroll
                    for (int fn = 0; fn < 4; ++fn) {
                        acc[fm][fn] = __builtin_amdgcn_mfma_f32_16x16x32_bf16(
                            ah[fm], bh[fn], acc[fm][fn], 0, 0, 0);
                        acc[fm][fn] = __builtin_amdgcn_mfma_f32_16x16x32_bf16(
                            al[fm], bh[fn], acc[fm][fn], 0, 0, 0);
                        acc[fm][fn] = __builtin_amdgcn_mfma_f32_16x16x32_bf16(
                            ah[fm], bl[fn], acc[fm][fn], 0, 0, 0);
                    }
            }
        }
    }
    float bv[4];
    #pragma unroll
    for (int fn = 0; fn < 4; ++fn) bv[fn] = bias[wn*64 + fn*16 + l15];
    #pragma unroll
    for (int fm = 0; fm < 2; ++fm)
        #pragma unroll
        for (int rg = 0; rg < 4; ++rg) {
            int px = wm*32 + fm*16 + q*4 + rg;
            int oy = oy0 + (px >> 6), ox = px & 63;
            float* o = out + (((size_t)(b*64) + oy)*64 + ox)*128;
            #pragma unroll
            for (int fn = 0; fn < 4; ++fn)
                o[wn*64 + fn*16 + l15] = gelu_f(acc[fm][fn][rg] + bv[fn]);
        }
}

// ---------------- conv3 (1x1, 128->64, f32): h2 -> z_e [65536,64]
__global__ __launch_bounds__(256) void k_conv3(const float* __restrict__ in,
        const float* __restrict__ w, const float* __restrict__ bias,
        float* __restrict__ out) {
    __shared__ __align__(16) float xs[128*33];
    __shared__ __align__(16) float wb[32*64];
    const int tid = threadIdx.x;
    const size_t pix0 = (size_t)blockIdx.x * 128;
    const int cg = tid & 7, pg = tid >> 3;
    const int c0a = cg*4, c0b = 32 + cg*4;
    const int p0 = pg*4;

    float acc[4][8];
    #pragma unroll
    for (int j = 0; j < 4; ++j)
        #pragma unroll
        for (int i = 0; i < 8; ++i) acc[j][i] = 0.f;

    for (int cs = 0; cs < 4; ++cs) {
        __syncthreads();
        for (int i = tid; i < 4096; i += 256) {
            int p = i >> 5, ci = i & 31;
            xs[p*33 + ci] = in[(pix0 + p)*128 + cs*32 + ci];
        }
        for (int i = tid; i < 2048; i += 256) {
            int ci = i >> 6, c = i & 63;
            wb[i] = w[(size_t)(cs*32 + ci)*64 + c];
        }
        __syncthreads();
        #pragma unroll 8
        for (int ci = 0; ci < 32; ++ci) {
            float a_[4];
            #pragma unroll
            for (int j = 0; j < 4; ++j) a_[j] = xs[(p0+j)*33 + ci];
            float4 b0 = *(const float4*)&wb[ci*64 + c0a];
            float4 b1 = *(const float4*)&wb[ci*64 + c0b];
            #pragma unroll
            for (int j = 0; j < 4; ++j) {
                acc[j][0] += a_[j]*b0.x; acc[j][1] += a_[j]*b0.y;
                acc[j][2] += a_[j]*b0.z; acc[j][3] += a_[j]*b0.w;
                acc[j][4] += a_[j]*b1.x; acc[j][5] += a_[j]*b1.y;
                acc[j][6] += a_[j]*b1.z; acc[j][7] += a_[j]*b1.w;
            }
        }
    }
    #pragma unroll
    for (int j = 0; j < 4; ++j) {
        float* o = out + (pix0 + p0 + j)*64;
        float4 va, vb;
        va.x = acc[j][0]+bias[c0a+0]; va.y = acc[j][1]+bias[c0a+1];
        va.z = acc[j][2]+bias[c0a+2]; va.w = acc[j][3]+bias[c0a+3];
        vb.x = acc[j][4]+bias[c0b+0]; vb.y = acc[j][5]+bias[c0b+1];
        vb.z = acc[j][6]+bias[c0b+2]; vb.w = acc[j][7]+bias[c0b+3];
        *(float4*)&o[c0a] = va;
        *(float4*)&o[c0b] = vb;
    }
}

// ---------------- VQ: f32 (exact), writes z_q as bf16 for the decoder
__global__ __launch_bounds__(256) void k_vq(const float* __restrict__ ze,
        const float* __restrict__ cb, unsigned short* __restrict__ zqb,
        float* __restrict__ tok, float* __restrict__ loss_acc) {
    __shared__ __align__(16) float zs[64*65];
    __shared__ __align__(16) float bt[64*132];
    __shared__ float es[128];
    __shared__ float z2s[64];
    __shared__ float rmin[64*16];
    __shared__ int   ridx[64*16];
    __shared__ int   widx[64];
    __shared__ float wsum[4];
    const int tid = threadIdx.x;
    const size_t tok0 = (size_t)blockIdx.x * 64;
    const int cg = tid & 15, pg = tid >> 4;
    const int k0a = cg*4, k0b = 64 + cg*4;
    const int t0 = pg*4;

    for (int i = tid; i < 4096; i += 256) {
        int tk = i >> 6, d = i & 63;
        zs[tk*65 + d] = ze[(tok0 + tk)*64 + d];
    }
    __syncthreads();
    if (tid < 64) {
        float s = 0.f;
        for (int d = 0; d < 64; ++d) { float v = zs[tid*65 + d]; s += v*v; }
        z2s[tid] = s;
    }

    float bmin[4] = {3.4e38f,3.4e38f,3.4e38f,3.4e38f};
    int   bidx[4] = {0,0,0,0};

    for (int ch = 0; ch < 8; ++ch) {
        __syncthreads();
        for (int i = tid; i < 8192; i += 256) {
            int k = i >> 6, d = i & 63;
            bt[d*132 + k] = cb[((size_t)(ch*128) + k)*64 + d];
        }
        __syncthreads();
        if (tid < 128) {
            float s = 0.f;
            for (int d = 0; d < 64; ++d) { float v = bt[d*132 + tid]; s += v*v; }
            es[tid] = s;
        }
        __syncthreads();
        float acc[4][8];
        #pragma unroll
        for (int j = 0; j < 4; ++j)
            #pragma unroll
            for (int i = 0; i < 8; ++i) acc[j][i] = 0.f;
        #pragma unroll 4
        for (int d = 0; d < 64; ++d) {
            float a_[4];
            #pragma unroll
            for (int j = 0; j < 4; ++j) a_[j] = zs[(t0+j)*65 + d];
            float4 b0 = *(const float4*)&bt[d*132 + k0a];
            float4 b1 = *(const float4*)&bt[d*132 + k0b];
            #pragma unroll
            for (int j = 0; j < 4; ++j) {
                acc[j][0] += a_[j]*b0.x; acc[j][1] += a_[j]*b0.y;
                acc[j][2] += a_[j]*b0.z; acc[j][3] += a_[j]*b0.w;
                acc[j][4] += a_[j]*b1.x; acc[j][5] += a_[j]*b1.y;
                acc[j][6] += a_[j]*b1.z; acc[j][7] += a_[j]*b1.w;
            }
        }
        #pragma unroll
        for (int j = 0; j < 4; ++j) {
            float z2 = z2s[t0+j];
            #pragma unroll
            for (int i = 0; i < 4; ++i) {
                float dist = (z2 + es[k0a+i]) - 2.f*acc[j][i];
                int idx = ch*128 + k0a + i;
                if (dist < bmin[j]) { bmin[j] = dist; bidx[j] = idx; }
            }
            #pragma unroll
            for (int i = 0; i < 4; ++i) {
                float dist = (z2 + es[k0b+i]) - 2.f*acc[j][4+i];
                int idx = ch*128 + k0b + i;
                if (dist < bmin[j]) { bmin[j] = dist; bidx[j] = idx; }
            }
        }
    }
    #pragma unroll
    for (int j = 0; j < 4; ++j) {
        rmin[(t0+j)*16 + cg] = bmin[j];
        ridx[(t0+j)*16 + cg] = bidx[j];
    }
    __syncthreads();
    if (tid < 64) {
        float bv = rmin[tid*16]; int bi = ridx[tid*16];
        for (int g = 1; g < 16; ++g) {
            float v = rmin[tid*16 + g]; int ii = ridx[tid*16 + g];
            if (v < bv || (v == bv && ii < bi)) { bv = v; bi = ii; }
        }
        widx[tid] = bi;
        tok[tok0 + tid] = (float)bi;
    }
    __syncthreads();
    float lsum = 0.f;
    for (int i = tid; i < 4096; i += 256) {
        int tk = i >> 6, d = i & 63;
        float v = cb[(size_t)widx[tk]*64 + d];
        zqb[(tok0 + tk)*64 + d] = f2bf(v);
        float diff = v - zs[tk*65 + d];
        lsum += diff*diff;
    }
    #pragma unroll
    for (int off = 32; off > 0; off >>= 1) lsum += __shfl_down(lsum, off, 64);
    if ((tid & 63) == 0) wsum[tid >> 6] = lsum;
    __syncthreads();
    if (tid == 0) atomicAdd(loss_acc, wsum[0]+wsum[1]+wsum[2]+wsum[3]);
}

// ---------------- weight prep kernels
__global__ __launch_bounds__(256) void k_wsplit2(const float* __restrict__ w,
        unsigned short* __restrict__ hi, unsigned short* __restrict__ lo) {
    int i = blockIdx.x*256 + threadIdx.x;        // 262144
    int rt = i >> 14, rem = i & 16383;
    int co = rem >> 7, ci = rem & 127;
    float v = w[((size_t)rt*128 + ci)*128 + co];
    unsigned short h = f2bf(v);
    hi[i] = h;
    lo[i] = f2bf(v - bf2f(h));
}
__global__ __launch_bounds__(256) void k_wcvt2(const float* __restrict__ w,
        unsigned short* __restrict__ o) {
    int i = blockIdx.x*256 + threadIdx.x;        // 262144
    int rt = i >> 14, rem = i & 16383;
    int co = rem >> 7, ci = rem & 127;
    o[i] = f2bf(w[((size_t)rt*128 + ci)*128 + co]);
}
__global__ __launch_bounds__(256) void k_wcvt1(const float* __restrict__ w,
        unsigned short* __restrict__ o) {
    int i = blockIdx.x*256 + threadIdx.x;        // 131072
    int rt = i >> 13, rem = i & 8191;
    int co = rem >> 6, ci = rem & 63;
    o[i] = f2bf(w[((size_t)rt*64 + ci)*128 + co]);
}

// ---------------- convT1 (bf16 MFMA, async16 staging): zqb -> g1b bf16, GELU
__global__ __launch_bounds__(256) void k_convt1m(const unsigned short* __restrict__ zqb,
        const unsigned short* __restrict__ w1b, const float* __restrict__ bias,
        const float* __restrict__ zsc, unsigned short* __restrict__ out) {
    __shared__ __align__(16) unsigned short A[2*128*32];
    __shared__ __align__(16) unsigned short Bm[2*128*32];
    const int tid = threadIdx.x;
    const int par = blockIdx.x & 1;
    const int ey  = (blockIdx.x >> 1) & 1;
    const int qq  = (blockIdx.x >> 2) & 31;
    const int b   = blockIdx.x >> 7;
    const int q0  = qq*2;
    const int lane = tid & 63, l15 = lane & 15, q = lane >> 4;
    const int wid = tid >> 6, wm = wid >> 1, wn = wid & 1;
    const int psub = lane >> 2;
    const int csub = (lane & 3) * 8;

    f32x4 acc[4][4];
    #pragma unroll
    for (int fm = 0; fm < 4; ++fm)
        #pragma unroll
        for (int fn = 0; fn < 4; ++fn) acc[fm][fn] = (f32x4){0.f,0.f,0.f,0.f};

    for (int tap = 0; tap < 4; ++tap) {
        int rr = tap >> 1, tt = tap & 1;
        int rt = (ey + 2*rr)*4 + (par + 2*tt);
        __syncthreads();
        #pragma unroll
        for (int j = 0; j < 8; ++j) {
            int id = wid*8 + j;               // 0..31, wave-uniform
            int kc = (id >> 3) & 1, s2 = id & 7;
            int ci = kc*32 + csub;
            if (id < 16) {
                int px = s2*16 + psub;
                int qv = q0 + (px >> 6), p = px & 63;
                int iy = qv + ey - 1 + rr, ix = p + par - 1 + tt;
                bool ok = (unsigned)iy < 64u && (unsigned)ix < 64u;
                const unsigned short* gp = ok
                    ? zqb + (((size_t)(b*64)+iy)*64+ix)*64 + ci
                    : (const unsigned short*)zsc;
                async16(gp, A + (kc*128 + s2*16)*32);
            } else {
                int co = s2*16 + psub;
                async16(w1b + ((size_t)rt*128 + co)*64 + ci,
                        Bm + (kc*128 + s2*16)*32);
            }
        }
        __syncthreads();
        #pragma unroll
        for (int kc = 0; kc < 2; ++kc) {
            short8 af[4], bf[4];
            #pragma unroll
            for (int fm = 0; fm < 4; ++fm)
                af[fm] = *(const short8*)&A[(kc*128 + wm*64 + fm*16 + l15)*32 + q*8];
            #pragma unroll
            for (int fn = 0; fn < 4; ++fn)
                bf[fn] = *(const short8*)&Bm[(kc*128 + wn*64 + fn*16 + l15)*32 + q*8];
            #pragma unroll
            for (int fm = 0; fm < 4; ++fm)
                #pragma unroll
                for (int fn = 0; fn < 4; ++fn)
                    acc[fm][fn] = __builtin_amdgcn_mfma_f32_16x16x32_bf16(
                        af[fm], bf[fn], acc[fm][fn], 0, 0, 0);
        }
    }
    float bv[4];
    #pragma unroll
    for (int fn = 0; fn < 4; ++fn) bv[fn] = bias[wn*64 + fn*16 + l15];
    #pragma unroll
    for (int fm = 0; fm < 4; ++fm)
        #pragma unroll
        for (int rg = 0; rg < 4; ++rg) {
            int px = wm*64 + fm*16 + q*4 + rg;
            int qv = q0 + (px >> 6), p = px & 63;
            int oy = 2*qv + ey, ox = par + 2*p;
            unsigned short* o = out + (((size_t)(b*128) + oy)*128 + ox)*128;
            #pragma unroll
            for (int fn = 0; fn < 4; ++fn)
                o[wn*64 + fn*16 + l15] = f2bf(gelu_fast(acc[fm][fn][rg] + bv[fn]));
        }
}

// ---------------- convT2 (bf16 MFMA, M=256 two adjacent qy rows) + fused 1x1
// Block (b,ey,par,qp): output rows oy=2(2qp)+ey and 2(2qp+1)+ey. Input rows
// {base, base+1, base+2} staged (middle shared). 512 thr, 8 waves 4Mx2N.
// LDS per kc phase: Araw[3][130][32] (24.96KB) + B4[4][128][32] (32KB).
__global__ __launch_bounds__(512) void k_convt2(const unsigned short* __restrict__ g1b,
        const unsigned short* __restrict__ wtb, const float* __restrict__ b2,
        const float* __restrict__ w3, const float* __restrict__ b3,
        const float* __restrict__ zsc, float* __restrict__ xrec) {
    union SM {
        struct {
            unsigned short Araw[3*130*32];   // 24960 B
            unsigned short B4[4*128*32];     // 32768 B
        } s;
        float red[256*2*3];                  // 6144 B
    };
    __shared__ __align__(16) union SM sm;
    const int tid = threadIdx.x;
    // XCD swizzle: consecutive same-XCD blocks walk par then qp (L2 row reuse)
    const int gblk = blockIdx.x;
    const int xcd = gblk & 7;
    const int s_  = gblk >> 3;                 // 0..511
    const int par = s_ & 1;
    const int qp  = (s_ >> 1) & 63;
    const int ey  = (s_ >> 7) & 1;
    const int b   = xcd*2 + (s_ >> 8);
    const int lane = tid & 63, l15 = lane & 15, q = lane >> 4;
    const int wid = tid >> 6;                  // 0..7
    const int wm = wid >> 1, wn = wid & 1;     // 4 M-waves x 2 N-waves
    const int rblk = wm >> 1;                  // which qy row (0/1)
    const int pxb  = (wm & 1)*64;              // px base within row
    const int ibase = 2*qp + ey - 1;           // first staged input row

    f32x4 acc[4][4];
    #pragma unroll
    for (int fm = 0; fm < 4; ++fm)
        #pragma unroll
        for (int fn = 0; fn < 4; ++fn) acc[fm][fn] = (f32x4){0.f,0.f,0.f,0.f};

    // zero halo cols (staged col 0 and 129, 3 rows x 4 qtrs) — 24 slots of 16B
    if (tid < 24) {
        int rr = tid >> 3, rem = tid & 7, side = rem >> 2, qtr = rem & 3;
        int col = side ? 129 : 0;
        *(uint4*)&sm.s.Araw[(rr*130 + col)*32 + qtr*8] = make_uint4(0,0,0,0);
    }

    // ---- hoisted staging descriptors ----
    // A: 3 chunks/thread. seg = wid*192 + j*64 + lane; 512 segs/row.
    const unsigned short* aptr[3];
    int astep[3];
    unsigned int aldst[3];
    #pragma unroll
    for (int j = 0; j < 3; ++j) {
        int s0 = wid*192 + j*64;
        int rsel = s0 >> 9;
        int w0 = s0 & 511;                     // multiple of 64
        int col = (w0 >> 2) + (lane >> 2);
        int iy = ibase + rsel;
        bool ok = (unsigned)iy < 128u;
        aptr[j] = ok
            ? g1b + (((size_t)(b*128) + iy)*128 + col)*128 + (lane & 3)*8
            : (const unsigned short*)zsc;
        astep[j] = ok ? 32 : 0;
        aldst[j] = (unsigned)(rsel*4160 + 32 + w0*8);   // ushort offset (wave-uniform)
    }
    // B: 4 chunks/thread. seg = wid*256 + j*64 + lane; 512 segs/tap.
    const unsigned short* bptr[4];
    unsigned int bldst[4];
    #pragma unroll
    for (int j = 0; j < 4; ++j) {
        int s0 = wid*256 + j*64;
        int tap = s0 >> 9;
        int w0 = s0 & 511;
        int co = (w0 >> 2) + (lane >> 2);
        int rr = tap >> 1, tt = tap & 1;
        int rt = (ey + 2*rr)*4 + (par + 2*tt);
        bptr[j] = wtb + ((size_t)rt*128 + co)*128 + (lane & 3)*8;
        bldst[j] = (unsigned)(tap*4096 + w0*8);
    }

    for (int kc = 0; kc < 4; ++kc) {
        __syncthreads();   // protect prior chunk's reads (and halo zeros, 1st)
        #pragma unroll
        for (int j = 0; j < 3; ++j) {
            async16(aptr[j], &sm.s.Araw[aldst[j]]);
            aptr[j] += astep[j];
        }
        #pragma unroll
        for (int j = 0; j < 4; ++j) {
            async16(bptr[j], &sm.s.B4[bldst[j]]);
            bptr[j] += 32;
        }
        __syncthreads();   // drain (compiler emits vmcnt(0))
        #pragma unroll
        for (int tap = 0; tap < 4; ++tap) {
            int rr = tap >> 1, tt = tap & 1;
            short8 af[4], bf[4];
            #pragma unroll
            for (int fm = 0; fm < 4; ++fm)
                af[fm] = *(const short8*)&sm.s.Araw[
                    ((rblk + rr)*130 + pxb + fm*16 + l15 + par + tt)*32 + q*8];
            #pragma unroll
            for (int fn = 0; fn < 4; ++fn)
                bf[fn] = *(const short8*)&sm.s.B4[
                    (tap*128 + wn*64 + fn*16 + l15)*32 + q*8];
            #pragma unroll
            for (int fm = 0; fm < 4; ++fm)
                #pragma unroll
                for (int fn = 0; fn < 4; ++fn)
                    acc[fm][fn] = __builtin_amdgcn_mfma_f32_16x16x32_bf16(
                        af[fm], bf[fn], acc[fm][fn], 0, 0, 0);
        }
    }

    // epilogue: GELU(acc+b2), project 128->3, shuffle-reduce over l15 (co dim)
    float b2v[4];
    float w3v[4][3];
    #pragma unroll
    for (int fn = 0; fn < 4; ++fn) {
        int co = wn*64 + fn*16 + l15;
        b2v[fn] = b2[co];
        w3v[fn][0] = w3[co*3+0]; w3v[fn][1] = w3[co*3+1]; w3v[fn][2] = w3[co*3+2];
    }
    __syncthreads();
    #pragma unroll
    for (int fm = 0; fm < 4; ++fm) {
        #pragma unroll
        for (int rg = 0; rg < 4; ++rg) {
            float s0 = 0.f, s1 = 0.f, s2 = 0.f;
            #pragma unroll
            for (int fn = 0; fn < 4; ++fn) {
                float y = gelu_fast(acc[fm][fn][rg] + b2v[fn]);
                s0 += y*w3v[fn][0]; s1 += y*w3v[fn][1]; s2 += y*w3v[fn][2];
            }
            #pragma unroll
            for (int m = 1; m < 16; m <<= 1) {
                s0 += __shfl_xor(s0, m, 64);
                s1 += __shfl_xor(s1, m, 64);
                s2 += __shfl_xor(s2, m, 64);
            }
            if (l15 == 0) {
                int px256 = wm*64 + fm*16 + q*4 + rg;    // rblk*128 + px
                sm.red[(px256*2 + wn)*3 + 0] = s0;
                sm.red[(px256*2 + wn)*3 + 1] = s1;
                sm.red[(px256*2 + wn)*3 + 2] = s2;
            }
        }
    }
    __syncthreads();
    for (int o = tid; o < 768; o += 512) {
        int px256 = o/3, jj = o - px256*3;
        int rb = px256 >> 7, px = px256 & 127;
        int oy = 2*(2*qp + rb) + ey;
        float s = b3[jj] + sm.red[(px256*2 + 0)*3 + jj] + sm.red[(px256*2 + 1)*3 + jj];
        xrec[(((size_t)(b*256) + oy)*256 + (par + 2*px))*3 + jj] = s;
    }
}

__global__ void k_zero(float* lacc, float* zsc) {
    if (threadIdx.x == 0) lacc[0] = 0.f;
    if (threadIdx.x < 4) zsc[threadIdx.x] = 0.f;
}

__global__ void k_finalize(const float* __restrict__ loss_acc, float* __restrict__ o) {
    if (threadIdx.x == 0) {
        float v = loss_acc[0] * (1.0f/4194304.0f);
        o[0] = v;
        o[1] = v;
    }
}

extern "C" void kernel_launch(void* const* d_in, const int* in_sizes, int n_in,
                              void* d_out, int out_size, void* d_ws, size_t ws_size,
                              hipStream_t stream) {
    (void)in_sizes; (void)n_in; (void)out_size; (void)ws_size;
    const float* x   = (const float*)d_in[0];
    const float* ew1 = (const float*)d_in[1];
    const float* eb1 = (const float*)d_in[2];
    const float* ew2 = (const float*)d_in[3];
    const float* eb2 = (const float*)d_in[4];
    const float* ew3 = (const float*)d_in[5];
    const float* eb3 = (const float*)d_in[6];
    const float* cb  = (const float*)d_in[7];
    const float* dw1 = (const float*)d_in[8];
    const float* db1 = (const float*)d_in[9];
    const float* dw2 = (const float*)d_in[10];
    const float* db2 = (const float*)d_in[11];
    const float* dw3 = (const float*)d_in[12];
    const float* db3 = (const float*)d_in[13];

    float* ws = (float*)d_ws;
    unsigned short* h1h  = (unsigned short*)(ws);                 // 33,554,432 us
    unsigned short* h1l  = (unsigned short*)(ws + 16777216);      // 33,554,432 us
    float*          h2   = ws + 33554432;                         //  8,388,608 f
    float*          ze   = ws + 41943040;                         //  4,194,304 f
    unsigned short* zqb  = (unsigned short*)(ws + 46137344);      //  4,194,304 us
    unsigned short* we2h = (unsigned short*)(ws + 48234496);      //    262,144 us
    unsigned short* we2l = (unsigned short*)(ws + 48365568);      //    262,144 us
    unsigned short* wd2b = (unsigned short*)(ws + 48496640);      //    262,144 us
    unsigned short* wd1b = (unsigned short*)(ws + 48627712);      //    131,072 us
    float*          lacc = ws + 48693248;                         //          1 f
    float*          zsc  = ws + 48693252;                         //  4 f (16B zeros)
    unsigned short* g1b  = h1h;   // reuse (dead after conv2m)

    float* xrec = (float*)d_out;            // 3,145,728 f
    float* tokf = xrec + 3145728;           //    65,536 f
    float* loss = tokf + 65536;             //         2 f

    k_zero    <<<   1,  64, 0, stream>>>(lacc, zsc);
    k_wsplit2 <<<1024, 256, 0, stream>>>(ew2, we2h, we2l);
    k_wcvt2   <<<1024, 256, 0, stream>>>(dw2, wd2b);
    k_wcvt1   <<< 512, 256, 0, stream>>>(dw1, wd1b);
    k_conv1   <<<4096, 256, 0, stream>>>(x, ew1, eb1, h1h, h1l);
    k_conv2m  <<< 512, 512, 0, stream>>>(h1h, h1l, we2h, we2l, eb2, zsc, h2);
    k_conv3   <<< 512, 256, 0, stream>>>(h2, ew3, eb3, ze);
    k_vq      <<<1024, 256, 0, stream>>>(ze, cb, zqb, tokf, lacc);
    k_convt1m <<<4096, 256, 0, stream>>>(zqb, wd1b, db1, zsc, g1b);
    k_convt2  <<<4096, 512, 0, stream>>>(g1b, wd2b, db2, dw3, db3, zsc, xrec);
    k_finalize<<<   1,  64, 0, stream>>>(lacc, loss);
}

// Round 11
// 589.064 us; speedup vs baseline: 1.8842x; 1.2311x over previous
//
#include <hip/hip_runtime.h>
#include <math.h>

// Shapes: B=16, x[16,256,256,3], h1[16,128,128,128], h2[16,64,64,128],
// z_e/z_q[65536,64], g1[16,128,128,128](bf16), x_rec[16,256,256,3], K=1024.
//
// R11: vq distance GEMM -> split-bf16 MFMA (k_vqm): argmin(e2-2*z.c) == ref
// argmin (z2 is per-token const). conv3 also emits z hi/lo bf16 planes;
// codebook pre-split + e2 pre-summed. convt1m -> M=256 (R10 lever: 512thr,
// 4 q-rows/block, barriers & B-bytes per output halved). Rest = R10.

typedef __attribute__((ext_vector_type(8))) short short8;
typedef __attribute__((ext_vector_type(4))) float f32x4;

__device__ __forceinline__ float gelu_f(float x) {          // encoder (exact path)
    float x3 = x*x*x;
    return 0.5f*x*(1.0f + tanhf(0.7978845608028654f*(x + 0.044715f*x3)));
}
__device__ __forceinline__ float gelu_fast(float x) {       // decoder only
    float t = __expf(-1.5957691216057308f*(x + 0.044715f*x*x*x));
    return x / (1.f + t);
}

__device__ __forceinline__ unsigned short f2bf(float f) {
    unsigned int u = __float_as_uint(f);
    u = (u + 0x7FFFu + ((u >> 16) & 1u)) >> 16;   // RNE
    return (unsigned short)u;
}
__device__ __forceinline__ float bf2f(unsigned short h) {
    return __uint_as_float(((unsigned int)h) << 16);
}

typedef const __attribute__((address_space(1))) unsigned int* gp_t;
typedef __attribute__((address_space(3))) unsigned int* lp_t;
__device__ __forceinline__ void async16(const void* g, void* l) {
    __builtin_amdgcn_global_load_lds((gp_t)g, (lp_t)l, 16, 0, 0);
}

// ---------------- conv1: x[16,256,256,3] -> h1 hi/lo bf16 planes, 4x4 s2 SAME, GELU
__global__ __launch_bounds__(256) void k_conv1(const float* __restrict__ x,
        const float* __restrict__ w, const float* __restrict__ bias,
        unsigned short* __restrict__ outh, unsigned short* __restrict__ outl) {
    __shared__ __align__(16) float ws[48*128];
    __shared__ __align__(16) float xs[4][390];
    const int tid = threadIdx.x;
    const int blk = blockIdx.x;
    const int oxt = blk & 1;
    const int oy  = (blk >> 1) & 127;
    const int b   = blk >> 8;
    const int cg = tid & 15, pg = tid >> 4;
    const int c0a = cg*4, c0b = 64 + cg*4;
    const int p0 = pg*4;
    const int ox0 = oxt*64;

    for (int i = tid; i < 6144; i += 256) ws[i] = w[i];
    for (int r = 0; r < 4; ++r) {
        int iy = 2*oy + r - 1;
        bool yok = (unsigned)iy < 256u;
        const float* xrow = x + ((size_t)(b*256) + iy)*256*3;
        for (int i = tid; i < 390; i += 256) {
            int ixl = i/3, ci = i - ixl*3;
            int ix = 2*ox0 - 1 + ixl;
            xs[r][i] = (yok && (unsigned)ix < 256u) ? xrow[(size_t)ix*3 + ci] : 0.f;
        }
    }
    __syncthreads();

    float acc[4][8];
    #pragma unroll
    for (int j = 0; j < 4; ++j)
        #pragma unroll
        for (int i = 0; i < 8; ++i) acc[j][i] = 0.f;

    #pragma unroll 6
    for (int pos = 0; pos < 48; ++pos) {
        int r = pos/12, tc = pos - r*12;
        int t = tc/3,  ci = tc - t*3;
        float4 w0 = *(const float4*)&ws[pos*128 + c0a];
        float4 w1 = *(const float4*)&ws[pos*128 + c0b];
        #pragma unroll
        for (int j = 0; j < 4; ++j) {
            float av = xs[r][(2*(p0+j) + t)*3 + ci];
            acc[j][0] += av*w0.x; acc[j][1] += av*w0.y;
            acc[j][2] += av*w0.z; acc[j][3] += av*w0.w;
            acc[j][4] += av*w1.x; acc[j][5] += av*w1.y;
            acc[j][6] += av*w1.z; acc[j][7] += av*w1.w;
        }
    }
    float bv[8];
    #pragma unroll
    for (int i = 0; i < 4; ++i) { bv[i] = bias[c0a+i]; bv[4+i] = bias[c0b+i]; }
    #pragma unroll
    for (int j = 0; j < 4; ++j) {
        int ox = ox0 + p0 + j;
        size_t base = (((size_t)(b*128) + oy)*128 + ox)*128;
        ushort4 ha, hb, la, lb;
        float y;
        y = gelu_f(acc[j][0]+bv[0]); ha.x = f2bf(y); la.x = f2bf(y - bf2f(ha.x));
        y = gelu_f(acc[j][1]+bv[1]); ha.y = f2bf(y); la.y = f2bf(y - bf2f(ha.y));
        y = gelu_f(acc[j][2]+bv[2]); ha.z = f2bf(y); la.z = f2bf(y - bf2f(ha.z));
        y = gelu_f(acc[j][3]+bv[3]); ha.w = f2bf(y); la.w = f2bf(y - bf2f(ha.w));
        y = gelu_f(acc[j][4]+bv[4]); hb.x = f2bf(y); lb.x = f2bf(y - bf2f(hb.x));
        y = gelu_f(acc[j][5]+bv[5]); hb.y = f2bf(y); lb.y = f2bf(y - bf2f(hb.y));
        y = gelu_f(acc[j][6]+bv[6]); hb.z = f2bf(y); lb.z = f2bf(y - bf2f(hb.z));
        y = gelu_f(acc[j][7]+bv[7]); hb.w = f2bf(y); lb.w = f2bf(y - bf2f(hb.w));
        *(ushort4*)&outh[base + c0a] = ha;
        *(ushort4*)&outh[base + c0b] = hb;
        *(ushort4*)&outl[base + c0a] = la;
        *(ushort4*)&outl[base + c0b] = lb;
    }
}

// ---------------- conv2 (split-bf16 MFMA, async16, 512 thr): h1 -> h2 f32, GELU
__global__ __launch_bounds__(512) void k_conv2m(const unsigned short* __restrict__ h1h,
        const unsigned short* __restrict__ h1l,
        const unsigned short* __restrict__ w2h, const unsigned short* __restrict__ w2l,
        const float* __restrict__ bias, const float* __restrict__ zsc,
        float* __restrict__ out) {
    __shared__ __align__(16) unsigned short Ah[2*128*32];
    __shared__ __align__(16) unsigned short Al[2*128*32];
    __shared__ __align__(16) unsigned short Bh[2*128*32];
    __shared__ __align__(16) unsigned short Bl[2*128*32];
    const int tid = threadIdx.x;
    const int yy = blockIdx.x & 31;
    const int b  = blockIdx.x >> 5;
    const int oy0 = yy*2;
    const int lane = tid & 63, l15 = lane & 15, q = lane >> 4;
    const int wid = tid >> 6;                  // 0..7
    const int wm = wid >> 1, wn = wid & 1;     // wave tile 32x64
    const int psub = lane >> 2;
    const int csub = (lane & 3) * 8;

    f32x4 acc[2][4];
    #pragma unroll
    for (int fm = 0; fm < 2; ++fm)
        #pragma unroll
        for (int fn = 0; fn < 4; ++fn) acc[fm][fn] = (f32x4){0.f,0.f,0.f,0.f};

    for (int tap = 0; tap < 16; ++tap) {
        int r = tap >> 2, t = tap & 3;
        for (int cs = 0; cs < 2; ++cs) {
            __syncthreads();
            #pragma unroll
            for (int j = 0; j < 8; ++j) {
                int id = wid*8 + j;           // 0..63, wave-uniform
                int plane = id >> 4;          // 0 Ah, 1 Al, 2 Bh, 3 Bl
                int kc_ = (id >> 3) & 1, s2 = id & 7;
                int ci = cs*64 + kc_*32 + csub;
                if (plane < 2) {
                    int px = s2*16 + psub;
                    int oyv = oy0 + (px >> 6), ox = px & 63;
                    int iy = 2*oyv + r - 1, ix = 2*ox + t - 1;
                    bool ok = (unsigned)iy < 128u && (unsigned)ix < 128u;
                    const unsigned short* base = plane ? h1l : h1h;
                    const unsigned short* gp = ok
                        ? base + (((size_t)(b*128)+iy)*128+ix)*128 + ci
                        : (const unsigned short*)zsc;
                    async16(gp, (plane ? Al : Ah) + (kc_*128 + s2*16)*32);
                } else {
                    int co = s2*16 + psub;
                    const unsigned short* base = (plane == 3) ? w2l : w2h;
                    async16(base + ((size_t)tap*128 + co)*128 + ci,
                            ((plane == 3) ? Bl : Bh) + (kc_*128 + s2*16)*32);
                }
            }
            __syncthreads();
            #pragma unroll
            for (int kc = 0; kc < 2; ++kc) {
                short8 ah[2], al[2], bh[4], bl[4];
                #pragma unroll
                for (int fm = 0; fm < 2; ++fm) {
                    int row = (kc*128 + wm*32 + fm*16 + l15)*32 + q*8;
                    ah[fm] = *(const short8*)&Ah[row];
                    al[fm] = *(const short8*)&Al[row];
                }
                #pragma unroll
                for (int fn = 0; fn < 4; ++fn) {
                    int row = (kc*128 + wn*64 + fn*16 + l15)*32 + q*8;
                    bh[fn] = *(const short8*)&Bh[row];
                    bl[fn] = *(const short8*)&Bl[row];
                }
                #pragma unroll
                for (int fm = 0; fm < 2; ++fm)
                    #pragma unroll
                    for (int fn = 0; fn < 4; ++fn) {
                        acc[fm][fn] = __builtin_amdgcn_mfma_f32_16x16x32_bf16(
                            ah[fm], bh[fn], acc[fm][fn], 0, 0, 0);
                        acc[fm][fn] = __builtin_amdgcn_mfma_f32_16x16x32_bf16(
                            al[fm], bh[fn], acc[fm][fn], 0, 0, 0);
                        acc[fm][fn] = __builtin_amdgcn_mfma_f32_16x16x32_bf16(
                            ah[fm], bl[fn], acc[fm][fn], 0, 0, 0);
                    }
            }
        }
    }
    float bv[4];
    #pragma unroll
    for (int fn = 0; fn < 4; ++fn) bv[fn] = bias[wn*64 + fn*16 + l15];
    #pragma unroll
    for (int fm = 0; fm < 2; ++fm)
        #pragma unroll
        for (int rg = 0; rg < 4; ++rg) {
            int px = wm*32 + fm*16 + q*4 + rg;
            int oy = oy0 + (px >> 6), ox = px & 63;
            float* o = out + (((size_t)(b*64) + oy)*64 + ox)*128;
            #pragma unroll
            for (int fn = 0; fn < 4; ++fn)
                o[wn*64 + fn*16 + l15] = gelu_f(acc[fm][fn][rg] + bv[fn]);
        }
}

// ---------------- conv3 (1x1, 128->64, f32): h2 -> z_e f32 + z hi/lo bf16
__global__ __launch_bounds__(256) void k_conv3(const float* __restrict__ in,
        const float* __restrict__ w, const float* __restrict__ bias,
        float* __restrict__ out, unsigned short* __restrict__ outzh,
        unsigned short* __restrict__ outzl) {
    __shared__ __align__(16) float xs[128*33];
    __shared__ __align__(16) float wb[32*64];
    const int tid = threadIdx.x;
    const size_t pix0 = (size_t)blockIdx.x * 128;
    const int cg = tid & 7, pg = tid >> 3;
    const int c0a = cg*4, c0b = 32 + cg*4;
    const int p0 = pg*4;

    float acc[4][8];
    #pragma unroll
    for (int j = 0; j < 4; ++j)
        #pragma unroll
        for (int i = 0; i < 8; ++i) acc[j][i] = 0.f;

    for (int cs = 0; cs < 4; ++cs) {
        __syncthreads();
        for (int i = tid; i < 4096; i += 256) {
            int p = i >> 5, ci = i & 31;
            xs[p*33 + ci] = in[(pix0 + p)*128 + cs*32 + ci];
        }
        for (int i = tid; i < 2048; i += 256) {
            int ci = i >> 6, c = i & 63;
            wb[i] = w[(size_t)(cs*32 + ci)*64 + c];
        }
        __syncthreads();
        #pragma unroll 8
        for (int ci = 0; ci < 32; ++ci) {
            float a_[4];
            #pragma unroll
            for (int j = 0; j < 4; ++j) a_[j] = xs[(p0+j)*33 + ci];
            float4 b0 = *(const float4*)&wb[ci*64 + c0a];
            float4 b1 = *(const float4*)&wb[ci*64 + c0b];
            #pragma unroll
            for (int j = 0; j < 4; ++j) {
                acc[j][0] += a_[j]*b0.x; acc[j][1] += a_[j]*b0.y;
                acc[j][2] += a_[j]*b0.z; acc[j][3] += a_[j]*b0.w;
                acc[j][4] += a_[j]*b1.x; acc[j][5] += a_[j]*b1.y;
                acc[j][6] += a_[j]*b1.z; acc[j][7] += a_[j]*b1.w;
            }
        }
    }
    #pragma unroll
    for (int j = 0; j < 4; ++j) {
        size_t base = (pix0 + p0 + j)*64;
        float v[8];
        #pragma unroll
        for (int i = 0; i < 4; ++i) { v[i] = acc[j][i]+bias[c0a+i]; v[4+i] = acc[j][4+i]+bias[c0b+i]; }
        float4 va = make_float4(v[0],v[1],v[2],v[3]);
        float4 vb = make_float4(v[4],v[5],v[6],v[7]);
        *(float4*)&out[base + c0a] = va;
        *(float4*)&out[base + c0b] = vb;
        ushort4 ha, la, hb, lb;
        ha.x = f2bf(v[0]); la.x = f2bf(v[0]-bf2f(ha.x));
        ha.y = f2bf(v[1]); la.y = f2bf(v[1]-bf2f(ha.y));
        ha.z = f2bf(v[2]); la.z = f2bf(v[2]-bf2f(ha.z));
        ha.w = f2bf(v[3]); la.w = f2bf(v[3]-bf2f(ha.w));
        hb.x = f2bf(v[4]); lb.x = f2bf(v[4]-bf2f(hb.x));
        hb.y = f2bf(v[5]); lb.y = f2bf(v[5]-bf2f(hb.y));
        hb.z = f2bf(v[6]); lb.z = f2bf(v[6]-bf2f(hb.z));
        hb.w = f2bf(v[7]); lb.w = f2bf(v[7]-bf2f(hb.w));
        *(ushort4*)&outzh[base + c0a] = ha;
        *(ushort4*)&outzh[base + c0b] = hb;
        *(ushort4*)&outzl[base + c0a] = la;
        *(ushort4*)&outzl[base + c0b] = lb;
    }
}

// ---------------- codebook prep: split + e2
__global__ __launch_bounds__(256) void k_wsplitcb(const float* __restrict__ cb,
        unsigned short* __restrict__ hi, unsigned short* __restrict__ lo) {
    int i = blockIdx.x*256 + threadIdx.x;      // 65536
    float v = cb[i];
    unsigned short h = f2bf(v);
    hi[i] = h;
    lo[i] = f2bf(v - bf2f(h));
}
__global__ __launch_bounds__(256) void k_e2(const float* __restrict__ cb,
        float* __restrict__ e2g) {
    int k = blockIdx.x*256 + threadIdx.x;      // 1024
    float s = 0.f;
    for (int d = 0; d < 64; ++d) { float v = cb[(size_t)k*64 + d]; s += v*v; }
    e2g[k] = s;
}

// ---------------- VQ (split-bf16 MFMA scores): argmin(e2 - 2 z.c) == ref argmin
// Block: 128 tokens x 1024 codes (8 chunks of 128), K=64. 256 thr, 4 waves 2Mx2N.
__global__ __launch_bounds__(256) void k_vqm(const unsigned short* __restrict__ zh,
        const unsigned short* __restrict__ zl, const unsigned short* __restrict__ cbh,
        const unsigned short* __restrict__ cbl, const float* __restrict__ e2g,
        const float* __restrict__ ze, const float* __restrict__ cb,
        unsigned short* __restrict__ zqb, float* __restrict__ tok,
        float* __restrict__ loss_acc) {
    __shared__ __align__(16) unsigned short Ah[2*128*32];
    __shared__ __align__(16) unsigned short Al[2*128*32];
    __shared__ __align__(16) unsigned short Bh[2*128*32];
    __shared__ __align__(16) unsigned short Bl[2*128*32];
    __shared__ float es[1024];
    __shared__ float cval[128*2];
    __shared__ int   cidx[128*2];
    __shared__ int   widx[128];
    __shared__ float wsum[4];
    const int tid = threadIdx.x;
    const size_t tok0 = (size_t)blockIdx.x * 128;
    const int lane = tid & 63, l15 = lane & 15, q = lane >> 4;
    const int wid = tid >> 6, wm = wid >> 1, wn = wid & 1;
    const int psub = lane >> 2, csub = (lane & 3)*8;

    // stage A (tokens, hi+lo) once: 32 segs, 8 per wave
    #pragma unroll
    for (int j = 0; j < 8; ++j) {
        int id = wid*8 + j;           // 0..31
        int pl = id >> 4;             // 0 Ah, 1 Al
        int kc = (id >> 3) & 1, s2 = id & 7;
        const unsigned short* src = (pl ? zl : zh)
            + (tok0 + s2*16 + psub)*64 + kc*32 + csub;
        async16(src, (pl ? Al : Ah) + (kc*128 + s2*16)*32);
    }
    for (int i = tid; i < 1024; i += 256) es[i] = e2g[i];

    float best[4][4];
    int   bidx[4][4];
    #pragma unroll
    for (int fm = 0; fm < 4; ++fm)
        #pragma unroll
        for (int rg = 0; rg < 4; ++rg) { best[fm][rg] = 3.4e38f; bidx[fm][rg] = 0; }

    for (int ch = 0; ch < 8; ++ch) {
        __syncthreads();              // drains A (1st iter) / prior B reads
        #pragma unroll
        for (int j = 0; j < 8; ++j) {
            int id = wid*8 + j;
            int pl = id >> 4;
            int kc = (id >> 3) & 1, s2 = id & 7;
            const unsigned short* src = (pl ? cbl : cbh)
                + ((size_t)(ch*128) + s2*16 + psub)*64 + kc*32 + csub;
            async16(src, (pl ? Bl : Bh) + (kc*128 + s2*16)*32);
        }
        __syncthreads();
        f32x4 acc[4][4];
        #pragma unroll
        for (int fm = 0; fm < 4; ++fm)
            #pragma unroll
            for (int fn = 0; fn < 4; ++fn) acc[fm][fn] = (f32x4){0.f,0.f,0.f,0.f};
        #pragma unroll
        for (int kc = 0; kc < 2; ++kc) {
            short8 ah[4], al[4], bh[4], bl[4];
            #pragma unroll
            for (int fm = 0; fm < 4; ++fm) {
                int row = (kc*128 + wm*64 + fm*16 + l15)*32 + q*8;
                ah[fm] = *(const short8*)&Ah[row];
                al[fm] = *(const short8*)&Al[row];
            }
            #pragma unroll
            for (int fn = 0; fn < 4; ++fn) {
                int row = (kc*128 + wn*64 + fn*16 + l15)*32 + q*8;
                bh[fn] = *(const short8*)&Bh[row];
                bl[fn] = *(const short8*)&Bl[row];
            }
            #pragma unroll
            for (int fm = 0; fm < 4; ++fm)
                #pragma unroll
                for (int fn = 0; fn < 4; ++fn) {
                    acc[fm][fn] = __builtin_amdgcn_mfma_f32_16x16x32_bf16(
                        ah[fm], bh[fn], acc[fm][fn], 0, 0, 0);
                    acc[fm][fn] = __builtin_amdgcn_mfma_f32_16x16x32_bf16(
                        al[fm], bh[fn], acc[fm][fn], 0, 0, 0);
                    acc[fm][fn] = __builtin_amdgcn_mfma_f32_16x16x32_bf16(
                        ah[fm], bl[fn], acc[fm][fn], 0, 0, 0);
                }
        }
        // scores + running argmin (codes ascending: fn asc; strict < = first-min)
        #pragma unroll
        for (int fm = 0; fm < 4; ++fm)
            #pragma unroll
            for (int fn = 0; fn < 4; ++fn) {
                int code = ch*128 + wn*64 + fn*16 + l15;
                float e2v = es[code];
                #pragma unroll
                for (int rg = 0; rg < 4; ++rg) {
                    float sc = e2v - 2.f*acc[fm][fn][rg];
                    if (sc < best[fm][rg]) { best[fm][rg] = sc; bidx[fm][rg] = code; }
                }
            }
    }

    // reduce over l15 (16 lanes hold disjoint codes for same token)
    #pragma unroll
    for (int fm = 0; fm < 4; ++fm)
        #pragma unroll
        for (int rg = 0; rg < 4; ++rg) {
            float bv = best[fm][rg]; int bi = bidx[fm][rg];
            #pragma unroll
            for (int m = 1; m < 16; m <<= 1) {
                float ov = __shfl_xor(bv, m, 64);
                int   oi = __shfl_xor(bi, m, 64);
                if (ov < bv || (ov == bv && oi < bi)) { bv = ov; bi = oi; }
            }
            if (l15 == 0) {
                int t = wm*64 + fm*16 + q*4 + rg;
                cval[t*2 + wn] = bv;
                cidx[t*2 + wn] = bi;
            }
        }
    __syncthreads();
    if (tid < 128) {
        float v0 = cval[tid*2], v1 = cval[tid*2 + 1];
        int   i0 = cidx[tid*2], i1 = cidx[tid*2 + 1];
        int bi = (v1 < v0) ? i1 : i0;     // tie -> lower code (wn=0) wins
        widx[tid] = bi;
        tok[tok0 + tid] = (float)bi;
    }
    __syncthreads();
    // zq write + commit loss (f32-exact, same as before)
    float lsum = 0.f;
    for (int i = tid; i < 8192; i += 256) {
        int tk = i >> 6, d = i & 63;
        float v = cb[(size_t)widx[tk]*64 + d];
        zqb[(tok0 + tk)*64 + d] = f2bf(v);
        float diff = v - ze[(tok0 + tk)*64 + d];
        lsum += diff*diff;
    }
    #pragma unroll
    for (int off = 32; off > 0; off >>= 1) lsum += __shfl_down(lsum, off, 64);
    if ((tid & 63) == 0) wsum[tid >> 6] = lsum;
    __syncthreads();
    if (tid == 0) atomicAdd(loss_acc, wsum[0]+wsum[1]+wsum[2]+wsum[3]);
}

// ---------------- weight prep kernels
__global__ __launch_bounds__(256) void k_wsplit2(const float* __restrict__ w,
        unsigned short* __restrict__ hi, unsigned short* __restrict__ lo) {
    int i = blockIdx.x*256 + threadIdx.x;        // 262144
    int rt = i >> 14, rem = i & 16383;
    int co = rem >> 7, ci = rem & 127;
    float v = w[((size_t)rt*128 + ci)*128 + co];
    unsigned short h = f2bf(v);
    hi[i] = h;
    lo[i] = f2bf(v - bf2f(h));
}
__global__ __launch_bounds__(256) void k_wcvt2(const float* __restrict__ w,
        unsigned short* __restrict__ o) {
    int i = blockIdx.x*256 + threadIdx.x;        // 262144
    int rt = i >> 14, rem = i & 16383;
    int co = rem >> 7, ci = rem & 127;
    o[i] = f2bf(w[((size_t)rt*128 + ci)*128 + co]);
}
__global__ __launch_bounds__(256) void k_wcvt1(const float* __restrict__ w,
        unsigned short* __restrict__ o) {
    int i = blockIdx.x*256 + threadIdx.x;        // 131072
    int rt = i >> 13, rem = i & 8191;
    int co = rem >> 6, ci = rem & 63;
    o[i] = f2bf(w[((size_t)rt*64 + ci)*128 + co]);
}

// ---------------- convT1 (bf16 MFMA, async16, M=256): zqb -> g1b bf16, GELU
// Block (b,ey,par,qt): 4 q-rows, M=256 px, N=128 co. 512 thr, 8 waves 4Mx2N.
__global__ __launch_bounds__(512) void k_convt1m(const unsigned short* __restrict__ zqb,
        const unsigned short* __restrict__ w1b, const float* __restrict__ bias,
        const float* __restrict__ zsc, unsigned short* __restrict__ out) {
    __shared__ __align__(16) unsigned short A[2*256*32];
    __shared__ __align__(16) unsigned short Bm[2*128*32];
    const int tid = threadIdx.x;
    const int par = blockIdx.x & 1;
    const int ey  = (blockIdx.x >> 1) & 1;
    const int qt  = (blockIdx.x >> 2) & 15;
    const int b   = blockIdx.x >> 6;
    const int q0  = qt*4;
    const int lane = tid & 63, l15 = lane & 15, q = lane >> 4;
    const int wid = tid >> 6, wm = wid >> 1, wn = wid & 1;
    const int psub = lane >> 2;
    const int csub = (lane & 3) * 8;

    f32x4 acc[4][4];
    #pragma unroll
    for (int fm = 0; fm < 4; ++fm)
        #pragma unroll
        for (int fn = 0; fn < 4; ++fn) acc[fm][fn] = (f32x4){0.f,0.f,0.f,0.f};

    for (int tap = 0; tap < 4; ++tap) {
        int rr = tap >> 1, tt = tap & 1;
        int rt = (ey + 2*rr)*4 + (par + 2*tt);
        __syncthreads();
        #pragma unroll
        for (int j = 0; j < 6; ++j) {
            int id = wid*6 + j;               // 0..47, wave-uniform
            if (id < 32) {                    // A: kc(2) x s2(16)
                int kc = id >> 4, s2 = id & 15;
                int px = s2*16 + psub;
                int qv = q0 + (px >> 6), p = px & 63;
                int iy = qv + ey - 1 + rr, ix = p + par - 1 + tt;
                bool ok = (unsigned)iy < 64u && (unsigned)ix < 64u;
                const unsigned short* gp = ok
                    ? zqb + (((size_t)(b*64)+iy)*64+ix)*64 + kc*32 + csub
                    : (const unsigned short*)zsc;
                async16(gp, A + (kc*256 + s2*16)*32);
            } else {                          // B: kc(2) x s2(8)
                int idb = id - 32;
                int kc = idb >> 3, s2 = idb & 7;
                int co = s2*16 + psub;
                async16(w1b + ((size_t)rt*128 + co)*64 + kc*32 + csub,
                        Bm + (kc*128 + s2*16)*32);
            }
        }
        __syncthreads();
        #pragma unroll
        for (int kc = 0; kc < 2; ++kc) {
            short8 af[4], bf[4];
            #pragma unroll
            for (int fm = 0; fm < 4; ++fm)
                af[fm] = *(const short8*)&A[(kc*256 + wm*64 + fm*16 + l15)*32 + q*8];
            #pragma unroll
            for (int fn = 0; fn < 4; ++fn)
                bf[fn] = *(const short8*)&Bm[(kc*128 + wn*64 + fn*16 + l15)*32 + q*8];
            #pragma unroll
            for (int fm = 0; fm < 4; ++fm)
                #pragma unroll
                for (int fn = 0; fn < 4; ++fn)
                    acc[fm][fn] = __builtin_amdgcn_mfma_f32_16x16x32_bf16(
                        af[fm], bf[fn], acc[fm][fn], 0, 0, 0);
        }
    }
    float bv[4];
    #pragma unroll
    for (int fn = 0; fn < 4; ++fn) bv[fn] = bias[wn*64 + fn*16 + l15];
    #pragma unroll
    for (int fm = 0; fm < 4; ++fm)
        #pragma unroll
        for (int rg = 0; rg < 4; ++rg) {
            int px = wm*64 + fm*16 + q*4 + rg;
            int qv = q0 + (px >> 6), p = px & 63;
            int oy = 2*qv + ey, ox = par + 2*p;
            unsigned short* o = out + (((size_t)(b*128) + oy)*128 + ox)*128;
            #pragma unroll
            for (int fn = 0; fn < 4; ++fn)
                o[wn*64 + fn*16 + l15] = f2bf(gelu_fast(acc[fm][fn][rg] + bv[fn]));
        }
}

// ---------------- convT2 (bf16 MFMA, M=256 two adjacent qy rows) + fused 1x1
__global__ __launch_bounds__(512) void k_convt2(const unsigned short* __restrict__ g1b,
        const unsigned short* __restrict__ wtb, const float* __restrict__ b2,
        const float* __restrict__ w3, const float* __restrict__ b3,
        const float* __restrict__ zsc, float* __restrict__ xrec) {
    union SM {
        struct {
            unsigned short Araw[3*130*32];   // 24960 B
            unsigned short B4[4*128*32];     // 32768 B
        } s;
        float red[256*2*3];                  // 6144 B
    };
    __shared__ __align__(16) union SM sm;
    const int tid = threadIdx.x;
    const int gblk = blockIdx.x;
    const int xcd = gblk & 7;
    const int s_  = gblk >> 3;                 // 0..511
    const int par = s_ & 1;
    const int qp  = (s_ >> 1) & 63;
    const int ey  = (s_ >> 7) & 1;
    const int b   = xcd*2 + (s_ >> 8);
    const int lane = tid & 63, l15 = lane & 15, q = lane >> 4;
    const int wid = tid >> 6;                  // 0..7
    const int wm = wid >> 1, wn = wid & 1;     // 4 M-waves x 2 N-waves
    const int rblk = wm >> 1;                  // which qy row (0/1)
    const int pxb  = (wm & 1)*64;              // px base within row
    const int ibase = 2*qp + ey - 1;           // first staged input row

    f32x4 acc[4][4];
    #pragma unroll
    for (int fm = 0; fm < 4; ++fm)
        #pragma unroll
        for (int fn = 0; fn < 4; ++fn) acc[fm][fn] = (f32x4){0.f,0.f,0.f,0.f};

    if (tid < 24) {
        int rr = tid >> 3, rem = tid & 7, side = rem >> 2, qtr = rem & 3;
        int col = side ? 129 : 0;
        *(uint4*)&sm.s.Araw[(rr*130 + col)*32 + qtr*8] = make_uint4(0,0,0,0);
    }

    const unsigned short* aptr[3];
    int astep[3];
    unsigned int aldst[3];
    #pragma unroll
    for (int j = 0; j < 3; ++j) {
        int s0 = wid*192 + j*64;
        int rsel = s0 >> 9;
        int w0 = s0 & 511;
        int col = (w0 >> 2) + (lane >> 2);
        int iy = ibase + rsel;
        bool ok = (unsigned)iy < 128u;
        aptr[j] = ok
            ? g1b + (((size_t)(b*128) + iy)*128 + col)*128 + (lane & 3)*8
            : (const unsigned short*)zsc;
        astep[j] = ok ? 32 : 0;
        aldst[j] = (unsigned)(rsel*4160 + 32 + w0*8);
    }
    const unsigned short* bptr[4];
    unsigned int bldst[4];
    #pragma unroll
    for (int j = 0; j < 4; ++j) {
        int s0 = wid*256 + j*64;
        int tap = s0 >> 9;
        int w0 = s0 & 511;
        int co = (w0 >> 2) + (lane >> 2);
        int rr = tap >> 1, tt = tap & 1;
        int rt = (ey + 2*rr)*4 + (par + 2*tt);
        bptr[j] = wtb + ((size_t)rt*128 + co)*128 + (lane & 3)*8;
        bldst[j] = (unsigned)(tap*4096 + w0*8);
    }

    for (int kc = 0; kc < 4; ++kc) {
        __syncthreads();
        #pragma unroll
        for (int j = 0; j < 3; ++j) {
            async16(aptr[j], &sm.s.Araw[aldst[j]]);
            aptr[j] += astep[j];
        }
        #pragma unroll
        for (int j = 0; j < 4; ++j) {
            async16(bptr[j], &sm.s.B4[bldst[j]]);
            bptr[j] += 32;
        }
        __syncthreads();
        #pragma unroll
        for (int tap = 0; tap < 4; ++tap) {
            int rr = tap >> 1, tt = tap & 1;
            short8 af[4], bf[4];
            #pragma unroll
            for (int fm = 0; fm < 4; ++fm)
                af[fm] = *(const short8*)&sm.s.Araw[
                    ((rblk + rr)*130 + pxb + fm*16 + l15 + par + tt)*32 + q*8];
            #pragma unroll
            for (int fn = 0; fn < 4; ++fn)
                bf[fn] = *(const short8*)&sm.s.B4[
                    (tap*128 + wn*64 + fn*16 + l15)*32 + q*8];
            #pragma unroll
            for (int fm = 0; fm < 4; ++fm)
                #pragma unroll
                for (int fn = 0; fn < 4; ++fn)
                    acc[fm][fn] = __builtin_amdgcn_mfma_f32_16x16x32_bf16(
                        af[fm], bf[fn], acc[fm][fn], 0, 0, 0);
        }
    }

    float b2v[4];
    float w3v[4][3];
    #pragma unroll
    for (int fn = 0; fn < 4; ++fn) {
        int co = wn*64 + fn*16 + l15;
        b2v[fn] = b2[co];
        w3v[fn][0] = w3[co*3+0]; w3v[fn][1] = w3[co*3+1]; w3v[fn][2] = w3[co*3+2];
    }
    __syncthreads();
    #pragma unroll
    for (int fm = 0; fm < 4; ++fm) {
        #pragma unroll
        for (int rg = 0; rg < 4; ++rg) {
            float s0 = 0.f, s1 = 0.f, s2 = 0.f;
            #pragma unroll
            for (int fn = 0; fn < 4; ++fn) {
                float y = gelu_fast(acc[fm][fn][rg] + b2v[fn]);
                s0 += y*w3v[fn][0]; s1 += y*w3v[fn][1]; s2 += y*w3v[fn][2];
            }
            #pragma unroll
            for (int m = 1; m < 16; m <<= 1) {
                s0 += __shfl_xor(s0, m, 64);
                s1 += __shfl_xor(s1, m, 64);
                s2 += __shfl_xor(s2, m, 64);
            }
            if (l15 == 0) {
                int px256 = wm*64 + fm*16 + q*4 + rg;
                sm.red[(px256*2 + wn)*3 + 0] = s0;
                sm.red[(px256*2 + wn)*3 + 1] = s1;
                sm.red[(px256*2 + wn)*3 + 2] = s2;
            }
        }
    }
    __syncthreads();
    for (int o = tid; o < 768; o += 512) {
        int px256 = o/3, jj = o - px256*3;
        int rb = px256 >> 7, px = px256 & 127;
        int oy = 2*(2*qp + rb) + ey;
        float s = b3[jj] + sm.red[(px256*2 + 0)*3 + jj] + sm.red[(px256*2 + 1)*3 + jj];
        xrec[(((size_t)(b*256) + oy)*256 + (par + 2*px))*3 + jj] = s;
    }
}

__global__ void k_zero(float* lacc, float* zsc) {
    if (threadIdx.x == 0) lacc[0] = 0.f;
    if (threadIdx.x < 4) zsc[threadIdx.x] = 0.f;
}

__global__ void k_finalize(const float* __restrict__ loss_acc, float* __restrict__ o) {
    if (threadIdx.x == 0) {
        float v = loss_acc[0] * (1.0f/4194304.0f);
        o[0] = v;
        o[1] = v;
    }
}

extern "C" void kernel_launch(void* const* d_in, const int* in_sizes, int n_in,
                              void* d_out, int out_size, void* d_ws, size_t ws_size,
                              hipStream_t stream) {
    (void)in_sizes; (void)n_in; (void)out_size; (void)ws_size;
    const float* x   = (const float*)d_in[0];
    const float* ew1 = (const float*)d_in[1];
    const float* eb1 = (const float*)d_in[2];
    const float* ew2 = (const float*)d_in[3];
    const float* eb2 = (const float*)d_in[4];
    const float* ew3 = (const float*)d_in[5];
    const float* eb3 = (const float*)d_in[6];
    const float* cb  = (const float*)d_in[7];
    const float* dw1 = (const float*)d_in[8];
    const float* db1 = (const float*)d_in[9];
    const float* dw2 = (const float*)d_in[10];
    const float* db2 = (const float*)d_in[11];
    const float* dw3 = (const float*)d_in[12];
    const float* db3 = (const float*)d_in[13];

    float* ws = (float*)d_ws;
    unsigned short* h1h  = (unsigned short*)(ws);                 // 33,554,432 us
    unsigned short* h1l  = (unsigned short*)(ws + 16777216);      // 33,554,432 us
    float*          h2   = ws + 33554432;                         //  8,388,608 f
    float*          ze   = ws + 41943040;                         //  4,194,304 f
    unsigned short* zqb  = (unsigned short*)(ws + 46137344);      //  4,194,304 us
    unsigned short* we2h = (unsigned short*)(ws + 48234496);      //    262,144 us
    unsigned short* we2l = (unsigned short*)(ws + 48365568);      //    262,144 us
    unsigned short* wd2b = (unsigned short*)(ws + 48496640);      //    262,144 us
    unsigned short* wd1b = (unsigned short*)(ws + 48627712);      //    131,072 us
    float*          lacc = ws + 48693248;                         //          1 f
    float*          zsc  = ws + 48693252;                         //  4 f (16B zeros)
    unsigned short* cbh  = (unsigned short*)(ws + 48693264);      //     65,536 us
    unsigned short* cbl  = (unsigned short*)(ws + 48726032);      //     65,536 us
    float*          e2g  = ws + 48758800;                         //      1,024 f
    unsigned short* g1b  = h1h;   // reuse (dead after conv2m)
    // z hi/lo planes live in the (dead after conv2m) h1l region:
    unsigned short* zh   = (unsigned short*)(ws + 16777216);      //  4,194,304 us
    unsigned short* zl   = (unsigned short*)(ws + 18874368);      //  4,194,304 us

    float* xrec = (float*)d_out;            // 3,145,728 f
    float* tokf = xrec + 3145728;           //    65,536 f
    float* loss = tokf + 65536;             //         2 f

    k_zero    <<<   1,  64, 0, stream>>>(lacc, zsc);
    k_wsplit2 <<<1024, 256, 0, stream>>>(ew2, we2h, we2l);
    k_wcvt2   <<<1024, 256, 0, stream>>>(dw2, wd2b);
    k_wcvt1   <<< 512, 256, 0, stream>>>(dw1, wd1b);
    k_wsplitcb<<< 256, 256, 0, stream>>>(cb, cbh, cbl);
    k_e2      <<<   4, 256, 0, stream>>>(cb, e2g);
    k_conv1   <<<4096, 256, 0, stream>>>(x, ew1, eb1, h1h, h1l);
    k_conv2m  <<< 512, 512, 0, stream>>>(h1h, h1l, we2h, we2l, eb2, zsc, h2);
    k_conv3   <<< 512, 256, 0, stream>>>(h2, ew3, eb3, ze, zh, zl);
    k_vqm     <<< 512, 256, 0, stream>>>(zh, zl, cbh, cbl, e2g, ze, cb, zqb, tokf, lacc);
    k_convt1m <<<1024, 512, 0, stream>>>(zqb, wd1b, db1, zsc, g1b);
    k_convt2  <<<4096, 512, 0, stream>>>(g1b, wd2b, db2, dw3, db3, zsc, xrec);
    k_finalize<<<   1,  64, 0, stream>>>(lacc, loss);
}